// Round 9
// baseline (418.527 us; speedup 1.0000x reference)
//
#include <hip/hip_runtime.h>
#include <hip/hip_bf16.h>
#include <stdint.h>

#define N_NODES 50000
#define N_EDGES 800000
#define TOT_EDGES (N_EDGES + N_NODES)
#define DIM 128
#define NEG 0.2f
#define BN_EPS 1e-5f
#define SKIPC 0.5f
#define NB 196          // buckets of 256 dst nodes
#define BCAP 6144       // per-bucket capacity (mean 4082, +31 sigma)

typedef __attribute__((ext_vector_type(8))) short short8;
typedef __attribute__((ext_vector_type(4))) float f32x4;

// ---------- helpers ----------
__device__ inline float bf2f(__hip_bfloat16 v) { return __bfloat162float(v); }
__device__ inline float u16f(unsigned short u) { return __uint_as_float(((unsigned int)u) << 16); }
__device__ inline unsigned short f2bu(float f) {
    __hip_bfloat16 b = __float2bfloat16(f);
    return *(unsigned short*)&b;
}
__device__ inline float4 load4f(const __hip_bfloat16* p) {
    const ushort4 u = *(const ushort4*)p;
    float4 r; r.x = u16f(u.x); r.y = u16f(u.y); r.z = u16f(u.z); r.w = u16f(u.w);
    return r;
}
__device__ inline void fma8(float* acc, float ex, uint4 u) {
    acc[0] += ex * u16f((unsigned short)(u.x & 0xFFFFu));
    acc[1] += ex * u16f((unsigned short)(u.x >> 16));
    acc[2] += ex * u16f((unsigned short)(u.y & 0xFFFFu));
    acc[3] += ex * u16f((unsigned short)(u.y >> 16));
    acc[4] += ex * u16f((unsigned short)(u.z & 0xFFFFu));
    acc[5] += ex * u16f((unsigned short)(u.z >> 16));
    acc[6] += ex * u16f((unsigned short)(u.w & 0xFFFFu));
    acc[7] += ex * u16f((unsigned short)(u.w >> 16));
}

// ---------- fallback (ws too small) ----------
__global__ void zero_out_k(unsigned short* out, int n) {
    int g = blockIdx.x * 256 + threadIdx.x;
    if (g < n) out[g] = 0;
}

// ---------- float dtype detection: fflag=1 => bf16, 0 => f32 ----------
__global__ void fdetect_k(const unsigned int* __restrict__ w0, int* __restrict__ fflag) {
    __shared__ int cs;
    if (threadIdx.x == 0) cs = 0;
    __syncthreads();
    unsigned int w = w0[threadIdx.x];
    float v0 = u16f((unsigned short)(w & 0xFFFFu));
    float a = fabsf(v0);
    int sane = (a < 2.0f && (a > 1e-20f || v0 == 0.0f)) ? 1 : 0;
    atomicAdd(&cs, sane);
    __syncthreads();
    if (threadIdx.x == 0) fflag[0] = (cs >= 128) ? 1 : 0;
}

// ---------- edge_index dtype detection: eflag=1 => int64, 0 => int32 ----------
__global__ void detect_k(const int* __restrict__ ei, int* __restrict__ eflag) {
    __shared__ int any;
    if (threadIdx.x == 0) any = 0;
    __syncthreads();
    int v = ei[2 * threadIdx.x + 1];
    if (v != 0) atomicOr(&any, 1);
    __syncthreads();
    if (threadIdx.x == 0) eflag[0] = (any == 0) ? 1 : 0;
}

// ---------- CSR build, bucketed ----------
__global__ __launch_bounds__(256) void binA_k(const int* __restrict__ ei,
                                              const int* __restrict__ eflag,
                                              int* __restrict__ bcnt,
                                              unsigned int* __restrict__ pairs) {
    __shared__ int cnt[NB], base[NB], cur[NB];
    int t = threadIdx.x;
    for (int i = t; i < NB; i += 256) cnt[i] = 0;
    __syncthreads();
    int f = eflag[0];
    int b0 = blockIdx.x * 4096;
    unsigned int pk[16];
    int bk[16];
    #pragma unroll
    for (int j = 0; j < 16; ++j) {
        int g = b0 + j * 256 + t;
        bk[j] = -1;
        if (g < N_EDGES) {
            int s, d;
            if (f) { s = ei[2 * g]; d = ei[2 * (N_EDGES + g)]; }
            else   { s = ei[g];     d = ei[N_EDGES + g]; }
            if ((unsigned)d < N_NODES && (unsigned)s < N_NODES) {
                bk[j] = d >> 8;
                pk[j] = (unsigned int)s | ((unsigned int)(d & 255) << 16);
                atomicAdd(&cnt[bk[j]], 1);
            }
        }
    }
    __syncthreads();
    if (t < NB) {
        int c = cnt[t];
        base[t] = c ? atomicAdd(&bcnt[t], c) : 0;
        cur[t] = 0;
    }
    __syncthreads();
    #pragma unroll
    for (int j = 0; j < 16; ++j) {
        if (bk[j] >= 0) {
            int off = base[bk[j]] + atomicAdd(&cur[bk[j]], 1);
            if (off < BCAP) pairs[(size_t)bk[j] * BCAP + off] = pk[j];
        }
    }
}

__global__ __launch_bounds__(256) void bucketscan_k(const int* __restrict__ bcnt,
                                                    int* __restrict__ bbase,
                                                    int* __restrict__ row_ptr) {
    __shared__ int sm[256];
    int t = threadIdx.x;
    int v = 0;
    if (t < NB) {
        int nn = min(256, N_NODES - t * 256);
        v = min(bcnt[t], BCAP) + nn;
    }
    sm[t] = v;
    __syncthreads();
    for (int off = 1; off < 256; off <<= 1) {
        int x = (t >= off) ? sm[t - off] : 0;
        __syncthreads();
        sm[t] += x;
        __syncthreads();
    }
    if (t < NB) bbase[t] = sm[t] - v;
    if (t == 255) row_ptr[N_NODES] = sm[255];
}

__global__ __launch_bounds__(256) void binB_k(const int* __restrict__ bcnt,
                                              const int* __restrict__ bbase,
                                              const unsigned int* __restrict__ pairs,
                                              int* __restrict__ row_ptr,
                                              int* __restrict__ ssrc) {
    __shared__ int cntL[256], scanL[256], curL[256];
    int b = blockIdx.x, t = threadIdx.x;
    int n0 = b * 256;
    int nn = min(256, N_NODES - n0);
    int cnt_b = min(bcnt[b], BCAP);
    const unsigned int* P = pairs + (size_t)b * BCAP;
    cntL[t] = (t < nn) ? 1 : 0;
    __syncthreads();
    for (int i = t; i < cnt_b; i += 256)
        atomicAdd(&cntL[P[i] >> 16], 1);
    __syncthreads();
    int v = cntL[t];
    scanL[t] = v;
    __syncthreads();
    for (int off = 1; off < 256; off <<= 1) {
        int x = (t >= off) ? scanL[t - off] : 0;
        __syncthreads();
        scanL[t] += x;
        __syncthreads();
    }
    int excl = scanL[t] - v;
    int gbase = bbase[b];
    if (t < nn) row_ptr[n0 + t] = gbase + excl;
    curL[t] = excl;
    __syncthreads();
    if (t < nn) {
        int pos = atomicAdd(&curL[t], 1);
        ssrc[gbase + pos] = n0 + t;
    }
    for (int i = t; i < cnt_b; i += 256) {
        unsigned int p = P[i];
        int pos = atomicAdd(&curL[p >> 16], 1);
        ssrc[gbase + pos] = (int)(p & 0xFFFFu);
    }
}

// ---------- W convert to bf16, SAME [M][K] layout ----------
__global__ void wconv_all_k(const void* __restrict__ W0, const void* __restrict__ W1,
                            const void* __restrict__ W2, unsigned short* __restrict__ Wb0,
                            unsigned short* __restrict__ Wb1, unsigned short* __restrict__ Wb2,
                            const int* __restrict__ fflag) {
    int f = fflag[0];
    int g = blockIdx.x * 256 + threadIdx.x;
    const void* W; unsigned short* Wb; int idx;
    if (g < 16384)        { W = W0; Wb = Wb0; idx = g; }
    else if (g < 32768)   { W = W1; Wb = Wb1; idx = g - 16384; }
    else if (g < 37888)   { W = W2; Wb = Wb2; idx = g - 32768; }
    else return;
    if (f) Wb[idx] = ((const unsigned short*)W)[idx];
    else   Wb[idx] = f2bu(((const float*)W)[idx]);
}

// ---------- fused small-param convert ----------
struct Cvt13 { const void* src[13]; float* dst[13]; int n[13]; };
__global__ void cvt_all_k(Cvt13 jobs, const int* __restrict__ fflag) {
    int f = fflag[0];
    int j = blockIdx.x;
    int n = jobs.n[j];
    const void* s = jobs.src[j];
    float* d = jobs.dst[j];
    for (int i = threadIdx.x; i < n; i += 256)
        d[i] = f ? bf2f(((const __hip_bfloat16*)s)[i]) : ((const float*)s)[i];
}

// ---------- MFMA GEMM (+ optional fused attention-logit epilogue) ----------
// Y[n][M] bf16 = X[n][128] @ W^T, W [M][128] bf16.
// A-frag/B-frag 16B contiguous; C/D: col=lane&15, row=quad*4+reg [m89].
// DO_AL (M=128,H=4,C=32): head(col)=t>>1; lane partial uses pAs[h*32+m] and
// pAs[h*32+16+m]; butterfly over the 16-lane m-group yields als/ald.
template<int MT, bool GUARDM, bool BF16IN, bool DO_AL>
__device__ inline void mfma_body(const unsigned short* __restrict__ Xb,
                                 const float* __restrict__ Xf,
                                 const unsigned short* __restrict__ Wb,
                                 unsigned short* __restrict__ Y,
                                 float* __restrict__ alsO, float* __restrict__ aldO,
                                 const float* __restrict__ pAs, const float* __restrict__ pAd,
                                 int n, int M) {
    int wave = (blockIdx.x * blockDim.x + threadIdx.x) >> 6;
    int r0 = wave * 16;
    if (r0 >= n) return;
    int lane = threadIdx.x & 63;
    int m = lane & 15, quad = lane >> 4;
    f32x4 acc[MT];
    #pragma unroll
    for (int t = 0; t < MT; ++t) acc[t] = (f32x4){0.f, 0.f, 0.f, 0.f};
    int arow = min(r0 + m, n - 1);

    #pragma unroll
    for (int kc = 0; kc < 4; ++kc) {
        int k0 = kc * 32 + quad * 8;
        short8 a;
        if (BF16IN) {
            a = *(const short8*)(Xb + (size_t)arow * 128 + k0);
        } else {
            const float* xp = Xf + (size_t)arow * 128 + k0;
            float4 x0 = *(const float4*)xp;
            float4 x1 = *(const float4*)(xp + 4);
            a[0] = (short)f2bu(x0.x); a[1] = (short)f2bu(x0.y);
            a[2] = (short)f2bu(x0.z); a[3] = (short)f2bu(x0.w);
            a[4] = (short)f2bu(x1.x); a[5] = (short)f2bu(x1.y);
            a[6] = (short)f2bu(x1.z); a[7] = (short)f2bu(x1.w);
        }
        #pragma unroll
        for (int t = 0; t < MT; ++t) {
            int col = t * 16 + m;
            short8 b;
            if (GUARDM && col >= M) {
                b = (short8){0,0,0,0,0,0,0,0};
            } else {
                b = *(const short8*)(Wb + (size_t)col * 128 + k0);
            }
            acc[t] = __builtin_amdgcn_mfma_f32_16x16x32_bf16(a, b, acc[t], 0, 0, 0);
        }
    }

    #pragma unroll
    for (int t = 0; t < MT; ++t) {
        int col = t * 16 + m;
        if (GUARDM && col >= M) continue;
        #pragma unroll
        for (int r = 0; r < 4; ++r) {
            int row = r0 + quad * 4 + r;
            if (row < n) Y[(size_t)row * M + col] = f2bu(acc[t][r]);
        }
    }

    if (DO_AL) {
        float pals[4][4], pald[4][4];
        #pragma unroll
        for (int hh = 0; hh < 4; ++hh) {
            float a0s = pAs[hh * 32 + m], a1s = pAs[hh * 32 + 16 + m];
            float a0d = pAd[hh * 32 + m], a1d = pAd[hh * 32 + 16 + m];
            #pragma unroll
            for (int r = 0; r < 4; ++r) {
                pals[r][hh] = acc[2 * hh][r] * a0s + acc[2 * hh + 1][r] * a1s;
                pald[r][hh] = acc[2 * hh][r] * a0d + acc[2 * hh + 1][r] * a1d;
            }
        }
        #pragma unroll
        for (int off = 1; off < 16; off <<= 1) {
            #pragma unroll
            for (int r = 0; r < 4; ++r)
                #pragma unroll
                for (int hh = 0; hh < 4; ++hh) {
                    pals[r][hh] += __shfl_xor(pals[r][hh], off, 64);
                    pald[r][hh] += __shfl_xor(pald[r][hh], off, 64);
                }
        }
        int rr = m >> 2, hh = m & 3;
        int node = r0 + quad * 4 + rr;
        if (node < n) {
            alsO[node * 4 + hh] = pals[rr][hh];
            aldO[node * 4 + hh] = pald[rr][hh];
        }
    }
}

__global__ __launch_bounds__(256) void mfma_x_k(const void* __restrict__ X,
                                                const unsigned short* __restrict__ Wb,
                                                unsigned short* __restrict__ Y,
                                                float* __restrict__ alsO, float* __restrict__ aldO,
                                                const float* __restrict__ pAs, const float* __restrict__ pAd,
                                                int n, const int* __restrict__ fflag) {
    if (fflag[0]) mfma_body<8, false, true, true>((const unsigned short*)X, nullptr, Wb, Y, alsO, aldO, pAs, pAd, n, 128);
    else          mfma_body<8, false, false, true>(nullptr, (const float*)X, Wb, Y, alsO, aldO, pAs, pAd, n, 128);
}

__global__ __launch_bounds__(256) void mfma_b_k(const unsigned short* __restrict__ X,
                                                const unsigned short* __restrict__ Wb,
                                                unsigned short* __restrict__ Y,
                                                float* __restrict__ alsO, float* __restrict__ aldO,
                                                const float* __restrict__ pAs, const float* __restrict__ pAd,
                                                int n) {
    mfma_body<8, false, true, true>(X, nullptr, Wb, Y, alsO, aldO, pAs, pAd, n, 128);
}

__global__ __launch_bounds__(256) void mfma_b40_k(const unsigned short* __restrict__ X,
                                                  const unsigned short* __restrict__ Wb,
                                                  unsigned short* __restrict__ Y, int n) {
    mfma_body<3, true, true, false>(X, nullptr, Wb, Y, nullptr, nullptr, nullptr, nullptr, n, 40);
}

// ---------- attention logits (final layer only) ----------
template<int H, int C>
__global__ void al_k(const __hip_bfloat16* __restrict__ hbuf, const float* __restrict__ as_,
                     const float* __restrict__ ad_, float* __restrict__ als,
                     float* __restrict__ ald, int n) {
    int g = blockIdx.x * 256 + threadIdx.x;
    if (g >= n * H) return;
    int node = g / H, hh = g % H;
    const __hip_bfloat16* hp = hbuf + (size_t)(node * H + hh) * C;
    float sa = 0.f, sd = 0.f;
    #pragma unroll
    for (int c = 0; c < C; c += 4) {
        float4 hv = load4f(hp + c);
        float4 av = *(const float4*)(as_ + hh * C + c);
        float4 dv = *(const float4*)(ad_ + hh * C + c);
        sa += hv.x * av.x + hv.y * av.y + hv.z * av.z + hv.w * av.w;
        sd += hv.x * dv.x + hv.y * dv.y + hv.z * dv.z + hv.w * dv.w;
    }
    als[g] = sa; ald[g] = sd;
}

// ---------- GAT aggregation v4: 2-deep pipelined gather ----------
template<int H, int C, int LPG, int CPL, bool FINAL>
__global__ __launch_bounds__(256) void agg4_k(const unsigned short* __restrict__ hbuf,
                                              const float* __restrict__ als,
                                              const float* __restrict__ ald,
                                              const float* __restrict__ bias,
                                              const int* __restrict__ row_ptr,
                                              const int* __restrict__ ssrc,
                                              void* __restrict__ out,
                                              const int* __restrict__ fflag, int n) {
    const int HC = H * C;
    const int G = 64 / LPG;
    const int NV = CPL / 8;
    int gw = (blockIdx.x * blockDim.x + threadIdx.x) >> 6;
    if (gw >= n) return;
    int lane = threadIdx.x & 63;
    int grp = lane / LPG;
    int sl  = lane % LPG;
    int c0 = sl * CPL;
    bool act = c0 < HC;
    int hl = act ? (c0 / C) : 0;
    int d = gw;
    int beg = row_ptr[d], end = row_ptr[d + 1];
    float adh = ald[d * H + hl];

    float denom = 0.f;
    float acc[CPL];
    #pragma unroll
    for (int j = 0; j < CPL; ++j) acc[j] = 0.f;

    // 2-deep pipeline: stages 0 (consume), 1, 2 (newly prefetched)
    int i0 = beg + grp;
    bool h0 = i0 < end;
    bool h1 = (i0 + G) < end;
    float al0 = 0.f, al1 = 0.f;
    uint4 u0[NV], u1[NV];
    if (h0) {
        int s = ssrc[i0];
        al0 = als[s * H + hl];
        if (act) {
            const uint4* hp = (const uint4*)(hbuf + (size_t)s * HC + c0);
            #pragma unroll
            for (int v = 0; v < NV; ++v) u0[v] = hp[v];
        }
    }
    if (h1) {
        int s = ssrc[i0 + G];
        al1 = als[s * H + hl];
        if (act) {
            const uint4* hp = (const uint4*)(hbuf + (size_t)s * HC + c0);
            #pragma unroll
            for (int v = 0; v < NV; ++v) u1[v] = hp[v];
        }
    }
    int inext = i0 + 2 * G;

    while (h0) {
        bool h2 = inext < end;
        float al2 = 0.f;
        uint4 u2[NV];
        if (h2) {
            int s = ssrc[inext];
            al2 = als[s * H + hl];
            if (act) {
                const uint4* hp = (const uint4*)(hbuf + (size_t)s * HC + c0);
                #pragma unroll
                for (int v = 0; v < NV; ++v) u2[v] = hp[v];
            }
        }
        // consume stage 0
        float t = al0 + adh;
        t = t > 0.f ? t : NEG * t;
        float ex = __expf(t);
        denom += ex;
        if (act) {
            #pragma unroll
            for (int v = 0; v < NV; ++v) fma8(acc + v * 8, ex, u0[v]);
        }
        // shift
        h0 = h1; al0 = al1;
        #pragma unroll
        for (int v = 0; v < NV; ++v) u0[v] = u1[v];
        h1 = h2; al1 = al2;
        #pragma unroll
        for (int v = 0; v < NV; ++v) u1[v] = u2[v];
        inext += G;
    }

    #pragma unroll
    for (int off = LPG; off < 64; off <<= 1) {
        denom += __shfl_xor(denom, off, 64);
        #pragma unroll
        for (int j = 0; j < CPL; ++j) acc[j] += __shfl_xor(acc[j], off, 64);
    }

    if (grp == 0 && act) {
        float inv = 1.f / denom;
        if (FINAL) {
            int bfout = fflag[0];
            #pragma unroll
            for (int j = 0; j < CPL; ++j) {
                float v = acc[j] * inv + bias[c0 + j];
                size_t idx = (size_t)d * HC + c0 + j;
                if (bfout) ((__hip_bfloat16*)out)[idx] = __float2bfloat16(v);
                else       ((float*)out)[idx] = v;
            }
        } else {
            float* of = (float*)out + (size_t)d * HC + c0;
            #pragma unroll
            for (int j = 0; j < CPL; ++j) of[j] = acc[j] * inv + bias[c0 + j];
        }
    }
}

// ---------- BatchNorm ----------
__global__ __launch_bounds__(256) void bn_stats_k(const float* __restrict__ x,
                                                  float* __restrict__ sum,
                                                  float* __restrict__ sumsq, int n) {
    __shared__ float ss[256], sq[256];
    int t = threadIdx.x;
    int c = t & 127, half = t >> 7;
    float s = 0.f, s2 = 0.f;
    for (int r = blockIdx.x * 2 + half; r < n; r += gridDim.x * 2) {
        float v = x[(size_t)r * 128 + c];
        s += v; s2 += v * v;
    }
    ss[t] = s; sq[t] = s2;
    __syncthreads();
    if (t < 128) {
        s = ss[t] + ss[t + 128];
        s2 = sq[t] + sq[t + 128];
        atomicAdd(&sum[c], s);
        atomicAdd(&sumsq[c], s2);
    }
}

__global__ void bn_apply_k(const float* __restrict__ x, const unsigned short* __restrict__ skip,
                           unsigned short* __restrict__ y, const float* __restrict__ sum,
                           const float* __restrict__ sumsq,
                           const float* __restrict__ g,
                           const float* __restrict__ be, int n) {
    int gid = blockIdx.x * 256 + threadIdx.x;
    if (gid >= n * 128) return;
    int c = gid & 127;
    const float invN = 1.f / (float)N_NODES;
    float mean = sum[c] * invN;
    float var = fmaxf(sumsq[c] * invN - mean * mean, 0.f);
    float inv = rsqrtf(var + BN_EPS);
    float v = (x[gid] - mean) * inv * g[c] + be[c];
    if (skip) v += SKIPC * u16f(skip[gid]);
    y[gid] = f2bu(fmaxf(v, 0.f));
}

// ---------- launch ----------
extern "C" void kernel_launch(void* const* d_in, const int* in_sizes, int n_in,
                              void* d_out, int out_size, void* d_ws, size_t ws_size,
                              hipStream_t stream) {
    const void* x   = d_in[0];
    const void* W0  = d_in[1];
    const void* as0 = d_in[2];
    const void* ad0 = d_in[3];
    const void* b0  = d_in[4];
    const void* g0  = d_in[5];
    const void* be0 = d_in[6];
    const void* W1  = d_in[7];
    const void* as1 = d_in[8];
    const void* ad1 = d_in[9];
    const void* b1  = d_in[10];
    const void* g1  = d_in[11];
    const void* be1 = d_in[12];
    const void* W2  = d_in[13];
    const void* as2 = d_in[14];
    const void* ad2 = d_in[15];
    const void* b2  = d_in[16];
    const int* ei = (const int*)d_in[17];

    char* w = (char*)d_ws;
    size_t off = 0;
    auto alloc = [&](size_t bytes) -> void* {
        void* p = w + off;
        off = (off + bytes + 255) & ~(size_t)255;
        return p;
    };
    float* hAgg = (float*)alloc((size_t)N_NODES * 128 * 4);
    unsigned short* hbf = (unsigned short*)alloc((size_t)N_NODES * 128 * 2);
    unsigned short* hS  = (unsigned short*)alloc((size_t)N_NODES * 128 * 2);
    unsigned short* hI  = (unsigned short*)alloc((size_t)N_NODES * 128 * 2);
    float* als = (float*)alloc((size_t)N_NODES * 4 * 4);
    float* ald = (float*)alloc((size_t)N_NODES * 4 * 4);
    unsigned short* Wb0 = (unsigned short*)alloc((size_t)128 * 128 * 2);
    unsigned short* Wb1 = (unsigned short*)alloc((size_t)128 * 128 * 2);
    unsigned short* Wb2 = (unsigned short*)alloc((size_t)40 * 128 * 2);
    float* prm = (float*)alloc(2048 * 4);
    float* bn  = (float*)alloc(256 * 4);
    int* row_ptr = (int*)alloc((size_t)(N_NODES + 1) * 4);
    int* ssrc    = (int*)alloc((size_t)TOT_EDGES * 4);
    unsigned int* pairs = (unsigned int*)alloc((size_t)NB * BCAP * 4);
    int* bcnt    = (int*)alloc((size_t)NB * 4);
    int* bbase   = (int*)alloc((size_t)NB * 4);
    int* eflag   = (int*)alloc(256);
    int* fflag   = (int*)alloc(256);
    float* bsum = bn, * bsq = bn + 128;

    float* pAs0 = prm + 0,   * pAd0 = prm + 128,  * pB0 = prm + 256;
    float* pG0  = prm + 384, * pBe0 = prm + 512;
    float* pAs1 = prm + 640, * pAd1 = prm + 768,  * pB1 = prm + 896;
    float* pG1  = prm + 1024,* pBe1 = prm + 1152;
    float* pAs2 = prm + 1280,* pAd2 = prm + 1320, * pB2 = prm + 1360;

    if (off > ws_size) {
        zero_out_k<<<(out_size + 255) / 256, 256, 0, stream>>>((unsigned short*)d_out, out_size);
        return;
    }

    const int MB = (((N_NODES + 15) / 16) + 3) / 4;
    const int AB = (N_NODES * 64 + 255) / 256;
    const int XB = (N_NODES * 128 + 255) / 256;

    // --- dtype detection + bucketed CSR build ---
    fdetect_k<<<1, 256, 0, stream>>>((const unsigned int*)W0, fflag);
    detect_k<<<1, 256, 0, stream>>>(ei, eflag);
    hipMemsetAsync(bcnt, 0, (size_t)NB * 4, stream);
    binA_k<<<(N_EDGES + 4095) / 4096, 256, 0, stream>>>(ei, eflag, bcnt, pairs);
    bucketscan_k<<<1, 256, 0, stream>>>(bcnt, bbase, row_ptr);
    binB_k<<<NB, 256, 0, stream>>>(bcnt, bbase, pairs, row_ptr, ssrc);

    // --- param conversion ---
    wconv_all_k<<<(37888 + 255) / 256, 256, 0, stream>>>(W0, W1, W2, Wb0, Wb1, Wb2, fflag);
    Cvt13 jobs;
    const void* srcs[13] = { as0, ad0, b0, g0, be0, as1, ad1, b1, g1, be1, as2, ad2, b2 };
    float* dsts[13] = { pAs0, pAd0, pB0, pG0, pBe0, pAs1, pAd1, pB1, pG1, pBe1, pAs2, pAd2, pB2 };
    int ns[13] = { 128,128,128,128,128, 128,128,128,128,128, 40,40,40 };
    for (int i = 0; i < 13; ++i) { jobs.src[i] = srcs[i]; jobs.dst[i] = dsts[i]; jobs.n[i] = ns[i]; }
    cvt_all_k<<<13, 256, 0, stream>>>(jobs, fflag);

    // --- layer 0 (GEMM + fused attention logits) ---
    mfma_x_k<<<MB, 256, 0, stream>>>(x, Wb0, hbf, als, ald, pAs0, pAd0, N_NODES, fflag);
    agg4_k<4, 32, 8, 16, false><<<AB, 256, 0, stream>>>(hbf, als, ald, pB0, row_ptr, ssrc, hAgg, fflag, N_NODES);
    hipMemsetAsync(bn, 0, 256 * 4, stream);
    bn_stats_k<<<256, 256, 0, stream>>>(hAgg, bsum, bsq, N_NODES);
    bn_apply_k<<<XB, 256, 0, stream>>>(hAgg, nullptr, hS, bsum, bsq, pG0, pBe0, N_NODES);
    // hS = relu(bn(...)) = skip (bf16)

    // --- layer 1 ---
    mfma_b_k<<<MB, 256, 0, stream>>>(hS, Wb1, hbf, als, ald, pAs1, pAd1, N_NODES);
    agg4_k<4, 32, 8, 16, false><<<AB, 256, 0, stream>>>(hbf, als, ald, pB1, row_ptr, ssrc, hAgg, fflag, N_NODES);
    hipMemsetAsync(bn, 0, 256 * 4, stream);
    bn_stats_k<<<256, 256, 0, stream>>>(hAgg, bsum, bsq, N_NODES);
    bn_apply_k<<<XB, 256, 0, stream>>>(hAgg, hS, hI, bsum, bsq, pG1, pBe1, N_NODES);
    // hI = relu(bn(...) + 0.5*skip) (bf16)

    // --- layer 2 ---
    mfma_b40_k<<<MB, 256, 0, stream>>>(hI, Wb2, hbf, N_NODES);
    al_k<1, 40><<<(N_NODES + 255) / 256, 256, 0, stream>>>((const __hip_bfloat16*)hbf, pAs2, pAd2, als, ald, N_NODES);
    agg4_k<1, 40, 8, 8, true><<<AB, 256, 0, stream>>>(hbf, als, ald, pB2, row_ptr, ssrc, d_out, fflag, N_NODES);
}

// Round 10
// 408.585 us; speedup vs baseline: 1.0243x; 1.0243x over previous
//
#include <hip/hip_runtime.h>
#include <hip/hip_bf16.h>
#include <stdint.h>

#define N_NODES 50000
#define N_EDGES 800000
#define TOT_EDGES (N_EDGES + N_NODES)
#define DIM 128
#define NEG 0.2f
#define BN_EPS 1e-5f
#define SKIPC 0.5f
#define NB 196          // buckets of 256 dst nodes
#define BCAP 6144       // per-bucket capacity (mean 4082, +31 sigma)

typedef __attribute__((ext_vector_type(8))) short short8;
typedef __attribute__((ext_vector_type(4))) float f32x4;

// ---------- helpers ----------
__device__ inline float bf2f(__hip_bfloat16 v) { return __bfloat162float(v); }
__device__ inline float u16f(unsigned short u) { return __uint_as_float(((unsigned int)u) << 16); }
__device__ inline unsigned short f2bu(float f) {
    __hip_bfloat16 b = __float2bfloat16(f);
    return *(unsigned short*)&b;
}
__device__ inline float4 load4f(const __hip_bfloat16* p) {
    const ushort4 u = *(const ushort4*)p;
    float4 r; r.x = u16f(u.x); r.y = u16f(u.y); r.z = u16f(u.z); r.w = u16f(u.w);
    return r;
}
__device__ inline void fma8(float* acc, float ex, uint4 u) {
    acc[0] += ex * u16f((unsigned short)(u.x & 0xFFFFu));
    acc[1] += ex * u16f((unsigned short)(u.x >> 16));
    acc[2] += ex * u16f((unsigned short)(u.y & 0xFFFFu));
    acc[3] += ex * u16f((unsigned short)(u.y >> 16));
    acc[4] += ex * u16f((unsigned short)(u.z & 0xFFFFu));
    acc[5] += ex * u16f((unsigned short)(u.z >> 16));
    acc[6] += ex * u16f((unsigned short)(u.w & 0xFFFFu));
    acc[7] += ex * u16f((unsigned short)(u.w >> 16));
}

// ---------- fallback (ws too small) ----------
__global__ void zero_out_k(unsigned short* out, int n) {
    int g = blockIdx.x * 256 + threadIdx.x;
    if (g < n) out[g] = 0;
}

// ---------- float dtype detection: fflag=1 => bf16, 0 => f32 ----------
__global__ void fdetect_k(const unsigned int* __restrict__ w0, int* __restrict__ fflag) {
    __shared__ int cs;
    if (threadIdx.x == 0) cs = 0;
    __syncthreads();
    unsigned int w = w0[threadIdx.x];
    float v0 = u16f((unsigned short)(w & 0xFFFFu));
    float a = fabsf(v0);
    int sane = (a < 2.0f && (a > 1e-20f || v0 == 0.0f)) ? 1 : 0;
    atomicAdd(&cs, sane);
    __syncthreads();
    if (threadIdx.x == 0) fflag[0] = (cs >= 128) ? 1 : 0;
}

// ---------- edge_index dtype detection: eflag=1 => int64, 0 => int32 ----------
__global__ void detect_k(const int* __restrict__ ei, int* __restrict__ eflag) {
    __shared__ int any;
    if (threadIdx.x == 0) any = 0;
    __syncthreads();
    int v = ei[2 * threadIdx.x + 1];
    if (v != 0) atomicOr(&any, 1);
    __syncthreads();
    if (threadIdx.x == 0) eflag[0] = (any == 0) ? 1 : 0;
}

// ---------- CSR build, bucketed ----------
__global__ __launch_bounds__(256) void binA_k(const int* __restrict__ ei,
                                              const int* __restrict__ eflag,
                                              int* __restrict__ bcnt,
                                              unsigned int* __restrict__ pairs) {
    __shared__ int cnt[NB], base[NB], cur[NB];
    int t = threadIdx.x;
    for (int i = t; i < NB; i += 256) cnt[i] = 0;
    __syncthreads();
    int f = eflag[0];
    int b0 = blockIdx.x * 4096;
    unsigned int pk[16];
    int bk[16];
    #pragma unroll
    for (int j = 0; j < 16; ++j) {
        int g = b0 + j * 256 + t;
        bk[j] = -1;
        if (g < N_EDGES) {
            int s, d;
            if (f) { s = ei[2 * g]; d = ei[2 * (N_EDGES + g)]; }
            else   { s = ei[g];     d = ei[N_EDGES + g]; }
            if ((unsigned)d < N_NODES && (unsigned)s < N_NODES) {
                bk[j] = d >> 8;
                pk[j] = (unsigned int)s | ((unsigned int)(d & 255) << 16);
                atomicAdd(&cnt[bk[j]], 1);
            }
        }
    }
    __syncthreads();
    if (t < NB) {
        int c = cnt[t];
        base[t] = c ? atomicAdd(&bcnt[t], c) : 0;
        cur[t] = 0;
    }
    __syncthreads();
    #pragma unroll
    for (int j = 0; j < 16; ++j) {
        if (bk[j] >= 0) {
            int off = base[bk[j]] + atomicAdd(&cur[bk[j]], 1);
            if (off < BCAP) pairs[(size_t)bk[j] * BCAP + off] = pk[j];
        }
    }
}

__global__ __launch_bounds__(256) void bucketscan_k(const int* __restrict__ bcnt,
                                                    int* __restrict__ bbase,
                                                    int* __restrict__ row_ptr) {
    __shared__ int sm[256];
    int t = threadIdx.x;
    int v = 0;
    if (t < NB) {
        int nn = min(256, N_NODES - t * 256);
        v = min(bcnt[t], BCAP) + nn;
    }
    sm[t] = v;
    __syncthreads();
    for (int off = 1; off < 256; off <<= 1) {
        int x = (t >= off) ? sm[t - off] : 0;
        __syncthreads();
        sm[t] += x;
        __syncthreads();
    }
    if (t < NB) bbase[t] = sm[t] - v;
    if (t == 255) row_ptr[N_NODES] = sm[255];
}

__global__ __launch_bounds__(256) void binB_k(const int* __restrict__ bcnt,
                                              const int* __restrict__ bbase,
                                              const unsigned int* __restrict__ pairs,
                                              int* __restrict__ row_ptr,
                                              int* __restrict__ ssrc) {
    __shared__ int cntL[256], scanL[256], curL[256];
    int b = blockIdx.x, t = threadIdx.x;
    int n0 = b * 256;
    int nn = min(256, N_NODES - n0);
    int cnt_b = min(bcnt[b], BCAP);
    const unsigned int* P = pairs + (size_t)b * BCAP;
    cntL[t] = (t < nn) ? 1 : 0;
    __syncthreads();
    for (int i = t; i < cnt_b; i += 256)
        atomicAdd(&cntL[P[i] >> 16], 1);
    __syncthreads();
    int v = cntL[t];
    scanL[t] = v;
    __syncthreads();
    for (int off = 1; off < 256; off <<= 1) {
        int x = (t >= off) ? scanL[t - off] : 0;
        __syncthreads();
        scanL[t] += x;
        __syncthreads();
    }
    int excl = scanL[t] - v;
    int gbase = bbase[b];
    if (t < nn) row_ptr[n0 + t] = gbase + excl;
    curL[t] = excl;
    __syncthreads();
    if (t < nn) {
        int pos = atomicAdd(&curL[t], 1);
        ssrc[gbase + pos] = n0 + t;
    }
    for (int i = t; i < cnt_b; i += 256) {
        unsigned int p = P[i];
        int pos = atomicAdd(&curL[p >> 16], 1);
        ssrc[gbase + pos] = (int)(p & 0xFFFFu);
    }
}

// ---------- W convert to bf16, SAME [M][K] layout ----------
__global__ void wconv_all_k(const void* __restrict__ W0, const void* __restrict__ W1,
                            const void* __restrict__ W2, unsigned short* __restrict__ Wb0,
                            unsigned short* __restrict__ Wb1, unsigned short* __restrict__ Wb2,
                            const int* __restrict__ fflag) {
    int f = fflag[0];
    int g = blockIdx.x * 256 + threadIdx.x;
    const void* W; unsigned short* Wb; int idx;
    if (g < 16384)        { W = W0; Wb = Wb0; idx = g; }
    else if (g < 32768)   { W = W1; Wb = Wb1; idx = g - 16384; }
    else if (g < 37888)   { W = W2; Wb = Wb2; idx = g - 32768; }
    else return;
    if (f) Wb[idx] = ((const unsigned short*)W)[idx];
    else   Wb[idx] = f2bu(((const float*)W)[idx]);
}

// ---------- fused small-param convert ----------
struct Cvt13 { const void* src[13]; float* dst[13]; int n[13]; };
__global__ void cvt_all_k(Cvt13 jobs, const int* __restrict__ fflag) {
    int f = fflag[0];
    int j = blockIdx.x;
    int n = jobs.n[j];
    const void* s = jobs.src[j];
    float* d = jobs.dst[j];
    for (int i = threadIdx.x; i < n; i += 256)
        d[i] = f ? bf2f(((const __hip_bfloat16*)s)[i]) : ((const float*)s)[i];
}

// ---------- MFMA GEMM: Y[n][M] bf16 = X[n][128] @ W^T, W [M][128] bf16 ----------
// (no fused epilogue — round-9's fused AL caused compiler LDS-backed private
//  arrays: 16KB LDS + 306k bank conflicts. Keep this kernel lean.)
template<int MT, bool GUARDM, bool BF16IN>
__device__ inline void mfma_body(const unsigned short* __restrict__ Xb,
                                 const float* __restrict__ Xf,
                                 const unsigned short* __restrict__ Wb,
                                 unsigned short* __restrict__ Y, int n, int M) {
    int wave = (blockIdx.x * blockDim.x + threadIdx.x) >> 6;
    int r0 = wave * 16;
    if (r0 >= n) return;
    int lane = threadIdx.x & 63;
    int m = lane & 15, quad = lane >> 4;
    f32x4 acc[MT];
    #pragma unroll
    for (int t = 0; t < MT; ++t) acc[t] = (f32x4){0.f, 0.f, 0.f, 0.f};
    int arow = min(r0 + m, n - 1);

    #pragma unroll
    for (int kc = 0; kc < 4; ++kc) {
        int k0 = kc * 32 + quad * 8;
        short8 a;
        if (BF16IN) {
            a = *(const short8*)(Xb + (size_t)arow * 128 + k0);
        } else {
            const float* xp = Xf + (size_t)arow * 128 + k0;
            float4 x0 = *(const float4*)xp;
            float4 x1 = *(const float4*)(xp + 4);
            a[0] = (short)f2bu(x0.x); a[1] = (short)f2bu(x0.y);
            a[2] = (short)f2bu(x0.z); a[3] = (short)f2bu(x0.w);
            a[4] = (short)f2bu(x1.x); a[5] = (short)f2bu(x1.y);
            a[6] = (short)f2bu(x1.z); a[7] = (short)f2bu(x1.w);
        }
        #pragma unroll
        for (int t = 0; t < MT; ++t) {
            int col = t * 16 + m;
            short8 b;
            if (GUARDM && col >= M) {
                b = (short8){0,0,0,0,0,0,0,0};
            } else {
                b = *(const short8*)(Wb + (size_t)col * 128 + k0);
            }
            acc[t] = __builtin_amdgcn_mfma_f32_16x16x32_bf16(a, b, acc[t], 0, 0, 0);
        }
    }

    #pragma unroll
    for (int t = 0; t < MT; ++t) {
        int col = t * 16 + m;
        if (GUARDM && col >= M) continue;
        #pragma unroll
        for (int r = 0; r < 4; ++r) {
            int row = r0 + quad * 4 + r;
            if (row < n) Y[(size_t)row * M + col] = f2bu(acc[t][r]);
        }
    }
}

__global__ __launch_bounds__(256) void mfma_x_k(const void* __restrict__ X,
                                                const unsigned short* __restrict__ Wb,
                                                unsigned short* __restrict__ Y, int n,
                                                const int* __restrict__ fflag) {
    if (fflag[0]) mfma_body<8, false, true>((const unsigned short*)X, nullptr, Wb, Y, n, 128);
    else          mfma_body<8, false, false>(nullptr, (const float*)X, Wb, Y, n, 128);
}

__global__ __launch_bounds__(256) void mfma_b_k(const unsigned short* __restrict__ X,
                                                const unsigned short* __restrict__ Wb,
                                                unsigned short* __restrict__ Y, int n) {
    mfma_body<8, false, true>(X, nullptr, Wb, Y, n, 128);
}

__global__ __launch_bounds__(256) void mfma_b40_k(const unsigned short* __restrict__ X,
                                                  const unsigned short* __restrict__ Wb,
                                                  unsigned short* __restrict__ Y, int n) {
    mfma_body<3, true, true>(X, nullptr, Wb, Y, n, 40);
}

// ---------- attention logits from bf16 h ----------
template<int H, int C>
__global__ void al_k(const __hip_bfloat16* __restrict__ hbuf, const float* __restrict__ as_,
                     const float* __restrict__ ad_, float* __restrict__ als,
                     float* __restrict__ ald, int n) {
    int g = blockIdx.x * 256 + threadIdx.x;
    if (g >= n * H) return;
    int node = g / H, hh = g % H;
    const __hip_bfloat16* hp = hbuf + (size_t)(node * H + hh) * C;
    float sa = 0.f, sd = 0.f;
    #pragma unroll
    for (int c = 0; c < C; c += 4) {
        float4 hv = load4f(hp + c);
        float4 av = *(const float4*)(as_ + hh * C + c);
        float4 dv = *(const float4*)(ad_ + hh * C + c);
        sa += hv.x * av.x + hv.y * av.y + hv.z * av.z + hv.w * av.w;
        sd += hv.x * dv.x + hv.y * dv.y + hv.z * dv.z + hv.w * dv.w;
    }
    als[g] = sa; ald[g] = sd;
}

// ---------- GAT aggregation v4: 2-deep pipelined gather ----------
template<int H, int C, int LPG, int CPL, bool FINAL>
__global__ __launch_bounds__(256) void agg4_k(const unsigned short* __restrict__ hbuf,
                                              const float* __restrict__ als,
                                              const float* __restrict__ ald,
                                              const float* __restrict__ bias,
                                              const int* __restrict__ row_ptr,
                                              const int* __restrict__ ssrc,
                                              void* __restrict__ out,
                                              const int* __restrict__ fflag, int n) {
    const int HC = H * C;
    const int G = 64 / LPG;
    const int NV = CPL / 8;
    int gw = (blockIdx.x * blockDim.x + threadIdx.x) >> 6;
    if (gw >= n) return;
    int lane = threadIdx.x & 63;
    int grp = lane / LPG;
    int sl  = lane % LPG;
    int c0 = sl * CPL;
    bool act = c0 < HC;
    int hl = act ? (c0 / C) : 0;
    int d = gw;
    int beg = row_ptr[d], end = row_ptr[d + 1];
    float adh = ald[d * H + hl];

    float denom = 0.f;
    float acc[CPL];
    #pragma unroll
    for (int j = 0; j < CPL; ++j) acc[j] = 0.f;

    // 2-deep pipeline
    int i0 = beg + grp;
    bool h0 = i0 < end;
    bool h1 = (i0 + G) < end;
    float al0 = 0.f, al1 = 0.f;
    uint4 u0[NV], u1[NV];
    if (h0) {
        int s = ssrc[i0];
        al0 = als[s * H + hl];
        if (act) {
            const uint4* hp = (const uint4*)(hbuf + (size_t)s * HC + c0);
            #pragma unroll
            for (int v = 0; v < NV; ++v) u0[v] = hp[v];
        }
    }
    if (h1) {
        int s = ssrc[i0 + G];
        al1 = als[s * H + hl];
        if (act) {
            const uint4* hp = (const uint4*)(hbuf + (size_t)s * HC + c0);
            #pragma unroll
            for (int v = 0; v < NV; ++v) u1[v] = hp[v];
        }
    }
    int inext = i0 + 2 * G;

    while (h0) {
        bool h2 = inext < end;
        float al2 = 0.f;
        uint4 u2[NV];
        if (h2) {
            int s = ssrc[inext];
            al2 = als[s * H + hl];
            if (act) {
                const uint4* hp = (const uint4*)(hbuf + (size_t)s * HC + c0);
                #pragma unroll
                for (int v = 0; v < NV; ++v) u2[v] = hp[v];
            }
        }
        float t = al0 + adh;
        t = t > 0.f ? t : NEG * t;
        float ex = __expf(t);
        denom += ex;
        if (act) {
            #pragma unroll
            for (int v = 0; v < NV; ++v) fma8(acc + v * 8, ex, u0[v]);
        }
        h0 = h1; al0 = al1;
        #pragma unroll
        for (int v = 0; v < NV; ++v) u0[v] = u1[v];
        h1 = h2; al1 = al2;
        #pragma unroll
        for (int v = 0; v < NV; ++v) u1[v] = u2[v];
        inext += G;
    }

    #pragma unroll
    for (int off = LPG; off < 64; off <<= 1) {
        denom += __shfl_xor(denom, off, 64);
        #pragma unroll
        for (int j = 0; j < CPL; ++j) acc[j] += __shfl_xor(acc[j], off, 64);
    }

    if (grp == 0 && act) {
        float inv = 1.f / denom;
        if (FINAL) {
            int bfout = fflag[0];
            #pragma unroll
            for (int j = 0; j < CPL; ++j) {
                float v = acc[j] * inv + bias[c0 + j];
                size_t idx = (size_t)d * HC + c0 + j;
                if (bfout) ((__hip_bfloat16*)out)[idx] = __float2bfloat16(v);
                else       ((float*)out)[idx] = v;
            }
        } else {
            float* of = (float*)out + (size_t)d * HC + c0;
            #pragma unroll
            for (int j = 0; j < CPL; ++j) of[j] = acc[j] * inv + bias[c0 + j];
        }
    }
}

// ---------- BatchNorm ----------
__global__ __launch_bounds__(256) void bn_stats_k(const float* __restrict__ x,
                                                  float* __restrict__ sum,
                                                  float* __restrict__ sumsq, int n) {
    __shared__ float ss[256], sq[256];
    int t = threadIdx.x;
    int c = t & 127, half = t >> 7;
    float s = 0.f, s2 = 0.f;
    for (int r = blockIdx.x * 2 + half; r < n; r += gridDim.x * 2) {
        float v = x[(size_t)r * 128 + c];
        s += v; s2 += v * v;
    }
    ss[t] = s; sq[t] = s2;
    __syncthreads();
    if (t < 128) {
        s = ss[t] + ss[t + 128];
        s2 = sq[t] + sq[t + 128];
        atomicAdd(&sum[c], s);
        atomicAdd(&sumsq[c], s2);
    }
}

__global__ void bn_apply_k(const float* __restrict__ x, const unsigned short* __restrict__ skip,
                           unsigned short* __restrict__ y, const float* __restrict__ sum,
                           const float* __restrict__ sumsq,
                           const float* __restrict__ g,
                           const float* __restrict__ be, int n) {
    int gid = blockIdx.x * 256 + threadIdx.x;
    if (gid >= n * 128) return;
    int c = gid & 127;
    const float invN = 1.f / (float)N_NODES;
    float mean = sum[c] * invN;
    float var = fmaxf(sumsq[c] * invN - mean * mean, 0.f);
    float inv = rsqrtf(var + BN_EPS);
    float v = (x[gid] - mean) * inv * g[c] + be[c];
    if (skip) v += SKIPC * u16f(skip[gid]);
    y[gid] = f2bu(fmaxf(v, 0.f));
}

// ---------- launch ----------
extern "C" void kernel_launch(void* const* d_in, const int* in_sizes, int n_in,
                              void* d_out, int out_size, void* d_ws, size_t ws_size,
                              hipStream_t stream) {
    const void* x   = d_in[0];
    const void* W0  = d_in[1];
    const void* as0 = d_in[2];
    const void* ad0 = d_in[3];
    const void* b0  = d_in[4];
    const void* g0  = d_in[5];
    const void* be0 = d_in[6];
    const void* W1  = d_in[7];
    const void* as1 = d_in[8];
    const void* ad1 = d_in[9];
    const void* b1  = d_in[10];
    const void* g1  = d_in[11];
    const void* be1 = d_in[12];
    const void* W2  = d_in[13];
    const void* as2 = d_in[14];
    const void* ad2 = d_in[15];
    const void* b2  = d_in[16];
    const int* ei = (const int*)d_in[17];

    char* w = (char*)d_ws;
    size_t off = 0;
    auto alloc = [&](size_t bytes) -> void* {
        void* p = w + off;
        off = (off + bytes + 255) & ~(size_t)255;
        return p;
    };
    float* hAgg = (float*)alloc((size_t)N_NODES * 128 * 4);
    unsigned short* hbf = (unsigned short*)alloc((size_t)N_NODES * 128 * 2);
    unsigned short* hS  = (unsigned short*)alloc((size_t)N_NODES * 128 * 2);
    unsigned short* hI  = (unsigned short*)alloc((size_t)N_NODES * 128 * 2);
    float* als = (float*)alloc((size_t)N_NODES * 4 * 4);
    float* ald = (float*)alloc((size_t)N_NODES * 4 * 4);
    unsigned short* Wb0 = (unsigned short*)alloc((size_t)128 * 128 * 2);
    unsigned short* Wb1 = (unsigned short*)alloc((size_t)128 * 128 * 2);
    unsigned short* Wb2 = (unsigned short*)alloc((size_t)40 * 128 * 2);
    float* prm = (float*)alloc(2048 * 4);
    float* bn  = (float*)alloc(256 * 4);
    int* row_ptr = (int*)alloc((size_t)(N_NODES + 1) * 4);
    int* ssrc    = (int*)alloc((size_t)TOT_EDGES * 4);
    unsigned int* pairs = (unsigned int*)alloc((size_t)NB * BCAP * 4);
    int* bcnt    = (int*)alloc((size_t)NB * 4);
    int* bbase   = (int*)alloc((size_t)NB * 4);
    int* eflag   = (int*)alloc(256);
    int* fflag   = (int*)alloc(256);
    float* bsum = bn, * bsq = bn + 128;

    float* pAs0 = prm + 0,   * pAd0 = prm + 128,  * pB0 = prm + 256;
    float* pG0  = prm + 384, * pBe0 = prm + 512;
    float* pAs1 = prm + 640, * pAd1 = prm + 768,  * pB1 = prm + 896;
    float* pG1  = prm + 1024,* pBe1 = prm + 1152;
    float* pAs2 = prm + 1280,* pAd2 = prm + 1320, * pB2 = prm + 1360;

    if (off > ws_size) {
        zero_out_k<<<(out_size + 255) / 256, 256, 0, stream>>>((unsigned short*)d_out, out_size);
        return;
    }

    const int MB = (((N_NODES + 15) / 16) + 3) / 4;
    const int AB = (N_NODES * 64 + 255) / 256;
    const int XB = (N_NODES * 128 + 255) / 256;

    // --- dtype detection + bucketed CSR build ---
    fdetect_k<<<1, 256, 0, stream>>>((const unsigned int*)W0, fflag);
    detect_k<<<1, 256, 0, stream>>>(ei, eflag);
    hipMemsetAsync(bcnt, 0, (size_t)NB * 4, stream);
    binA_k<<<(N_EDGES + 4095) / 4096, 256, 0, stream>>>(ei, eflag, bcnt, pairs);
    bucketscan_k<<<1, 256, 0, stream>>>(bcnt, bbase, row_ptr);
    binB_k<<<NB, 256, 0, stream>>>(bcnt, bbase, pairs, row_ptr, ssrc);

    // --- param conversion ---
    wconv_all_k<<<(37888 + 255) / 256, 256, 0, stream>>>(W0, W1, W2, Wb0, Wb1, Wb2, fflag);
    Cvt13 jobs;
    const void* srcs[13] = { as0, ad0, b0, g0, be0, as1, ad1, b1, g1, be1, as2, ad2, b2 };
    float* dsts[13] = { pAs0, pAd0, pB0, pG0, pBe0, pAs1, pAd1, pB1, pG1, pBe1, pAs2, pAd2, pB2 };
    int ns[13] = { 128,128,128,128,128, 128,128,128,128,128, 40,40,40 };
    for (int i = 0; i < 13; ++i) { jobs.src[i] = srcs[i]; jobs.dst[i] = dsts[i]; jobs.n[i] = ns[i]; }
    cvt_all_k<<<13, 256, 0, stream>>>(jobs, fflag);

    // --- layer 0 ---
    mfma_x_k<<<MB, 256, 0, stream>>>(x, Wb0, hbf, N_NODES, fflag);
    al_k<4, 32><<<(N_NODES * 4 + 255) / 256, 256, 0, stream>>>((const __hip_bfloat16*)hbf, pAs0, pAd0, als, ald, N_NODES);
    agg4_k<4, 32, 8, 16, false><<<AB, 256, 0, stream>>>(hbf, als, ald, pB0, row_ptr, ssrc, hAgg, fflag, N_NODES);
    hipMemsetAsync(bn, 0, 256 * 4, stream);
    bn_stats_k<<<256, 256, 0, stream>>>(hAgg, bsum, bsq, N_NODES);
    bn_apply_k<<<XB, 256, 0, stream>>>(hAgg, nullptr, hS, bsum, bsq, pG0, pBe0, N_NODES);
    // hS = relu(bn(...)) = skip (bf16)

    // --- layer 1 ---
    mfma_b_k<<<MB, 256, 0, stream>>>(hS, Wb1, hbf, N_NODES);
    al_k<4, 32><<<(N_NODES * 4 + 255) / 256, 256, 0, stream>>>((const __hip_bfloat16*)hbf, pAs1, pAd1, als, ald, N_NODES);
    agg4_k<4, 32, 8, 16, false><<<AB, 256, 0, stream>>>(hbf, als, ald, pB1, row_ptr, ssrc, hAgg, fflag, N_NODES);
    hipMemsetAsync(bn, 0, 256 * 4, stream);
    bn_stats_k<<<256, 256, 0, stream>>>(hAgg, bsum, bsq, N_NODES);
    bn_apply_k<<<XB, 256, 0, stream>>>(hAgg, hS, hI, bsum, bsq, pG1, pBe1, N_NODES);
    // hI = relu(bn(...) + 0.5*skip) (bf16)

    // --- layer 2 ---
    mfma_b40_k<<<MB, 256, 0, stream>>>(hI, Wb2, hbf, N_NODES);
    al_k<1, 40><<<(N_NODES + 255) / 256, 256, 0, stream>>>((const __hip_bfloat16*)hbf, pAs2, pAd2, als, ald, N_NODES);
    agg4_k<1, 40, 8, 8, true><<<AB, 256, 0, stream>>>(hbf, als, ald, pB2, row_ptr, ssrc, d_out, fflag, N_NODES);
}

// Round 11
// 386.285 us; speedup vs baseline: 1.0835x; 1.0577x over previous
//
#include <hip/hip_runtime.h>
#include <hip/hip_bf16.h>
#include <stdint.h>

#define N_NODES 50000
#define N_EDGES 800000
#define TOT_EDGES (N_EDGES + N_NODES)
#define DIM 128
#define NEG 0.2f
#define BN_EPS 1e-5f
#define SKIPC 0.5f
#define NB 196          // buckets of 256 dst nodes
#define BCAP 6144       // per-bucket capacity (mean 4082, +31 sigma)

typedef __attribute__((ext_vector_type(8))) short short8;
typedef __attribute__((ext_vector_type(4))) float f32x4;

// ---------- helpers ----------
__device__ inline float bf2f(__hip_bfloat16 v) { return __bfloat162float(v); }
__device__ inline float u16f(unsigned short u) { return __uint_as_float(((unsigned int)u) << 16); }
__device__ inline unsigned short f2bu(float f) {
    __hip_bfloat16 b = __float2bfloat16(f);
    return *(unsigned short*)&b;
}
__device__ inline float4 load4f(const __hip_bfloat16* p) {
    const ushort4 u = *(const ushort4*)p;
    float4 r; r.x = u16f(u.x); r.y = u16f(u.y); r.z = u16f(u.z); r.w = u16f(u.w);
    return r;
}
__device__ inline void fma8(float* acc, float ex, uint4 u) {
    acc[0] += ex * u16f((unsigned short)(u.x & 0xFFFFu));
    acc[1] += ex * u16f((unsigned short)(u.x >> 16));
    acc[2] += ex * u16f((unsigned short)(u.y & 0xFFFFu));
    acc[3] += ex * u16f((unsigned short)(u.y >> 16));
    acc[4] += ex * u16f((unsigned short)(u.z & 0xFFFFu));
    acc[5] += ex * u16f((unsigned short)(u.z >> 16));
    acc[6] += ex * u16f((unsigned short)(u.w & 0xFFFFu));
    acc[7] += ex * u16f((unsigned short)(u.w >> 16));
}
__device__ inline unsigned int pk2(float a, float b) {
    return (unsigned int)f2bu(a) | ((unsigned int)f2bu(b) << 16);
}

// ---------- fallback (ws too small) ----------
__global__ void zero_out_k(unsigned short* out, int n) {
    int g = blockIdx.x * 256 + threadIdx.x;
    if (g < n) out[g] = 0;
}

// ---------- float dtype detection: fflag=1 => bf16, 0 => f32 ----------
__global__ void fdetect_k(const unsigned int* __restrict__ w0, int* __restrict__ fflag) {
    __shared__ int cs;
    if (threadIdx.x == 0) cs = 0;
    __syncthreads();
    unsigned int w = w0[threadIdx.x];
    float v0 = u16f((unsigned short)(w & 0xFFFFu));
    float a = fabsf(v0);
    int sane = (a < 2.0f && (a > 1e-20f || v0 == 0.0f)) ? 1 : 0;
    atomicAdd(&cs, sane);
    __syncthreads();
    if (threadIdx.x == 0) fflag[0] = (cs >= 128) ? 1 : 0;
}

// ---------- CSR build, bucketed ----------
// Self-detects edge dtype: int64 => all odd int32 words of first 16 entries are 0.
__global__ __launch_bounds__(256) void binA_k(const int* __restrict__ ei,
                                              int* __restrict__ bcnt,
                                              unsigned int* __restrict__ pairs) {
    __shared__ int cnt[NB], base[NB], cur[NB];
    __shared__ int sf;
    int t = threadIdx.x;
    if (t == 0) sf = 0;
    for (int i = t; i < NB; i += 256) cnt[i] = 0;
    __syncthreads();
    if (t < 16 && ei[2 * t + 1] != 0) atomicOr(&sf, 1);
    __syncthreads();
    int f = (sf == 0);   // 1 => int64
    int b0 = blockIdx.x * 4096;
    unsigned int pk[16];
    int bk[16];
    #pragma unroll
    for (int j = 0; j < 16; ++j) {
        int g = b0 + j * 256 + t;
        bk[j] = -1;
        if (g < N_EDGES) {
            int s, d;
            if (f) { s = ei[2 * g]; d = ei[2 * (N_EDGES + g)]; }
            else   { s = ei[g];     d = ei[N_EDGES + g]; }
            if ((unsigned)d < N_NODES && (unsigned)s < N_NODES) {
                bk[j] = d >> 8;
                pk[j] = (unsigned int)s | ((unsigned int)(d & 255) << 16);
                atomicAdd(&cnt[bk[j]], 1);
            }
        }
    }
    __syncthreads();
    if (t < NB) {
        int c = cnt[t];
        base[t] = c ? atomicAdd(&bcnt[t], c) : 0;
        cur[t] = 0;
    }
    __syncthreads();
    #pragma unroll
    for (int j = 0; j < 16; ++j) {
        if (bk[j] >= 0) {
            int off = base[bk[j]] + atomicAdd(&cur[bk[j]], 1);
            if (off < BCAP) pairs[(size_t)bk[j] * BCAP + off] = pk[j];
        }
    }
}

__global__ __launch_bounds__(256) void bucketscan_k(const int* __restrict__ bcnt,
                                                    int* __restrict__ bbase,
                                                    int* __restrict__ row_ptr) {
    __shared__ int sm[256];
    int t = threadIdx.x;
    int v = 0;
    if (t < NB) {
        int nn = min(256, N_NODES - t * 256);
        v = min(bcnt[t], BCAP) + nn;
    }
    sm[t] = v;
    __syncthreads();
    for (int off = 1; off < 256; off <<= 1) {
        int x = (t >= off) ? sm[t - off] : 0;
        __syncthreads();
        sm[t] += x;
        __syncthreads();
    }
    if (t < NB) bbase[t] = sm[t] - v;
    if (t == 255) row_ptr[N_NODES] = sm[255];
}

__global__ __launch_bounds__(256) void binB_k(const int* __restrict__ bcnt,
                                              const int* __restrict__ bbase,
                                              const unsigned int* __restrict__ pairs,
                                              int* __restrict__ row_ptr,
                                              int* __restrict__ ssrc) {
    __shared__ int cntL[256], scanL[256], curL[256];
    int b = blockIdx.x, t = threadIdx.x;
    int n0 = b * 256;
    int nn = min(256, N_NODES - n0);
    int cnt_b = min(bcnt[b], BCAP);
    const unsigned int* P = pairs + (size_t)b * BCAP;
    cntL[t] = (t < nn) ? 1 : 0;
    __syncthreads();
    for (int i = t; i < cnt_b; i += 256)
        atomicAdd(&cntL[P[i] >> 16], 1);
    __syncthreads();
    int v = cntL[t];
    scanL[t] = v;
    __syncthreads();
    for (int off = 1; off < 256; off <<= 1) {
        int x = (t >= off) ? scanL[t - off] : 0;
        __syncthreads();
        scanL[t] += x;
        __syncthreads();
    }
    int excl = scanL[t] - v;
    int gbase = bbase[b];
    if (t < nn) row_ptr[n0 + t] = gbase + excl;
    curL[t] = excl;
    __syncthreads();
    if (t < nn) {
        int pos = atomicAdd(&curL[t], 1);
        ssrc[gbase + pos] = n0 + t;
    }
    for (int i = t; i < cnt_b; i += 256) {
        unsigned int p = P[i];
        int pos = atomicAdd(&curL[p >> 16], 1);
        ssrc[gbase + pos] = (int)(p & 0xFFFFu);
    }
}

// ---------- W convert to bf16, SAME [M][K] layout ----------
__global__ void wconv_all_k(const void* __restrict__ W0, const void* __restrict__ W1,
                            const void* __restrict__ W2, unsigned short* __restrict__ Wb0,
                            unsigned short* __restrict__ Wb1, unsigned short* __restrict__ Wb2,
                            const int* __restrict__ fflag) {
    int f = fflag[0];
    int g = blockIdx.x * 256 + threadIdx.x;
    const void* W; unsigned short* Wb; int idx;
    if (g < 16384)        { W = W0; Wb = Wb0; idx = g; }
    else if (g < 32768)   { W = W1; Wb = Wb1; idx = g - 16384; }
    else if (g < 37888)   { W = W2; Wb = Wb2; idx = g - 32768; }
    else return;
    if (f) Wb[idx] = ((const unsigned short*)W)[idx];
    else   Wb[idx] = f2bu(((const float*)W)[idx]);
}

// ---------- fused small-param convert ----------
struct Cvt13 { const void* src[13]; float* dst[13]; int n[13]; };
__global__ void cvt_all_k(Cvt13 jobs, const int* __restrict__ fflag) {
    int f = fflag[0];
    int j = blockIdx.x;
    int n = jobs.n[j];
    const void* s = jobs.src[j];
    float* d = jobs.dst[j];
    for (int i = threadIdx.x; i < n; i += 256)
        d[i] = f ? bf2f(((const __hip_bfloat16*)s)[i]) : ((const float*)s)[i];
}

// ---------- MFMA GEMM: Y[n][M] bf16 = X[n][128] @ W^T, W [M][128] bf16 ----------
template<int MT, bool GUARDM, bool BF16IN>
__device__ inline void mfma_body(const unsigned short* __restrict__ Xb,
                                 const float* __restrict__ Xf,
                                 const unsigned short* __restrict__ Wb,
                                 unsigned short* __restrict__ Y, int n, int M) {
    int wave = (blockIdx.x * blockDim.x + threadIdx.x) >> 6;
    int r0 = wave * 16;
    if (r0 >= n) return;
    int lane = threadIdx.x & 63;
    int m = lane & 15, quad = lane >> 4;
    f32x4 acc[MT];
    #pragma unroll
    for (int t = 0; t < MT; ++t) acc[t] = (f32x4){0.f, 0.f, 0.f, 0.f};
    int arow = min(r0 + m, n - 1);

    #pragma unroll
    for (int kc = 0; kc < 4; ++kc) {
        int k0 = kc * 32 + quad * 8;
        short8 a;
        if (BF16IN) {
            a = *(const short8*)(Xb + (size_t)arow * 128 + k0);
        } else {
            const float* xp = Xf + (size_t)arow * 128 + k0;
            float4 x0 = *(const float4*)xp;
            float4 x1 = *(const float4*)(xp + 4);
            a[0] = (short)f2bu(x0.x); a[1] = (short)f2bu(x0.y);
            a[2] = (short)f2bu(x0.z); a[3] = (short)f2bu(x0.w);
            a[4] = (short)f2bu(x1.x); a[5] = (short)f2bu(x1.y);
            a[6] = (short)f2bu(x1.z); a[7] = (short)f2bu(x1.w);
        }
        #pragma unroll
        for (int t = 0; t < MT; ++t) {
            int col = t * 16 + m;
            short8 b;
            if (GUARDM && col >= M) {
                b = (short8){0,0,0,0,0,0,0,0};
            } else {
                b = *(const short8*)(Wb + (size_t)col * 128 + k0);
            }
            acc[t] = __builtin_amdgcn_mfma_f32_16x16x32_bf16(a, b, acc[t], 0, 0, 0);
        }
    }

    #pragma unroll
    for (int t = 0; t < MT; ++t) {
        int col = t * 16 + m;
        if (GUARDM && col >= M) continue;
        #pragma unroll
        for (int r = 0; r < 4; ++r) {
            int row = r0 + quad * 4 + r;
            if (row < n) Y[(size_t)row * M + col] = f2bu(acc[t][r]);
        }
    }
}

__global__ __launch_bounds__(256) void mfma_x_k(const void* __restrict__ X,
                                                const unsigned short* __restrict__ Wb,
                                                unsigned short* __restrict__ Y, int n,
                                                const int* __restrict__ fflag) {
    if (fflag[0]) mfma_body<8, false, true>((const unsigned short*)X, nullptr, Wb, Y, n, 128);
    else          mfma_body<8, false, false>(nullptr, (const float*)X, Wb, Y, n, 128);
}

__global__ __launch_bounds__(256) void mfma_b_k(const unsigned short* __restrict__ X,
                                                const unsigned short* __restrict__ Wb,
                                                unsigned short* __restrict__ Y, int n) {
    mfma_body<8, false, true>(X, nullptr, Wb, Y, n, 128);
}

__global__ __launch_bounds__(256) void mfma_b40_k(const unsigned short* __restrict__ X,
                                                  const unsigned short* __restrict__ Wb,
                                                  unsigned short* __restrict__ Y, int n) {
    mfma_body<3, true, true>(X, nullptr, Wb, Y, n, 40);
}

// ---------- attention logits from bf16 h ----------
template<int H, int C>
__global__ void al_k(const __hip_bfloat16* __restrict__ hbuf, const float* __restrict__ as_,
                     const float* __restrict__ ad_, float* __restrict__ als,
                     float* __restrict__ ald, int n) {
    int g = blockIdx.x * 256 + threadIdx.x;
    if (g >= n * H) return;
    int node = g / H, hh = g % H;
    const __hip_bfloat16* hp = hbuf + (size_t)(node * H + hh) * C;
    float sa = 0.f, sd = 0.f;
    #pragma unroll
    for (int c = 0; c < C; c += 4) {
        float4 hv = load4f(hp + c);
        float4 av = *(const float4*)(as_ + hh * C + c);
        float4 dv = *(const float4*)(ad_ + hh * C + c);
        sa += hv.x * av.x + hv.y * av.y + hv.z * av.z + hv.w * av.w;
        sd += hv.x * dv.x + hv.y * dv.y + hv.z * dv.z + hv.w * dv.w;
    }
    als[g] = sa; ald[g] = sd;
}

// ---------- GAT aggregation: 2-deep pipelined gather, bf16 output ----------
template<int H, int C, int LPG, int CPL, bool FINAL>
__global__ __launch_bounds__(256) void agg4_k(const unsigned short* __restrict__ hbuf,
                                              const float* __restrict__ als,
                                              const float* __restrict__ ald,
                                              const float* __restrict__ bias,
                                              const int* __restrict__ row_ptr,
                                              const int* __restrict__ ssrc,
                                              void* __restrict__ out,
                                              const int* __restrict__ fflag, int n) {
    const int HC = H * C;
    const int G = 64 / LPG;
    const int NV = CPL / 8;
    int gw = (blockIdx.x * blockDim.x + threadIdx.x) >> 6;
    if (gw >= n) return;
    int lane = threadIdx.x & 63;
    int grp = lane / LPG;
    int sl  = lane % LPG;
    int c0 = sl * CPL;
    bool act = c0 < HC;
    int hl = act ? (c0 / C) : 0;
    int d = gw;
    int beg = row_ptr[d], end = row_ptr[d + 1];
    float adh = ald[d * H + hl];

    float denom = 0.f;
    float acc[CPL];
    #pragma unroll
    for (int j = 0; j < CPL; ++j) acc[j] = 0.f;

    int i0 = beg + grp;
    bool h0 = i0 < end;
    bool h1 = (i0 + G) < end;
    float al0 = 0.f, al1 = 0.f;
    uint4 u0[NV], u1[NV];
    if (h0) {
        int s = ssrc[i0];
        al0 = als[s * H + hl];
        if (act) {
            const uint4* hp = (const uint4*)(hbuf + (size_t)s * HC + c0);
            #pragma unroll
            for (int v = 0; v < NV; ++v) u0[v] = hp[v];
        }
    }
    if (h1) {
        int s = ssrc[i0 + G];
        al1 = als[s * H + hl];
        if (act) {
            const uint4* hp = (const uint4*)(hbuf + (size_t)s * HC + c0);
            #pragma unroll
            for (int v = 0; v < NV; ++v) u1[v] = hp[v];
        }
    }
    int inext = i0 + 2 * G;

    while (h0) {
        bool h2 = inext < end;
        float al2 = 0.f;
        uint4 u2[NV];
        if (h2) {
            int s = ssrc[inext];
            al2 = als[s * H + hl];
            if (act) {
                const uint4* hp = (const uint4*)(hbuf + (size_t)s * HC + c0);
                #pragma unroll
                for (int v = 0; v < NV; ++v) u2[v] = hp[v];
            }
        }
        float t = al0 + adh;
        t = t > 0.f ? t : NEG * t;
        float ex = __expf(t);
        denom += ex;
        if (act) {
            #pragma unroll
            for (int v = 0; v < NV; ++v) fma8(acc + v * 8, ex, u0[v]);
        }
        h0 = h1; al0 = al1;
        #pragma unroll
        for (int v = 0; v < NV; ++v) u0[v] = u1[v];
        h1 = h2; al1 = al2;
        #pragma unroll
        for (int v = 0; v < NV; ++v) u1[v] = u2[v];
        inext += G;
    }

    #pragma unroll
    for (int off = LPG; off < 64; off <<= 1) {
        denom += __shfl_xor(denom, off, 64);
        #pragma unroll
        for (int j = 0; j < CPL; ++j) acc[j] += __shfl_xor(acc[j], off, 64);
    }

    if (grp == 0 && act) {
        float inv = 1.f / denom;
        float vals[CPL];
        #pragma unroll
        for (int j = 0; j < CPL; ++j) vals[j] = acc[j] * inv + bias[c0 + j];
        if (FINAL && !fflag[0]) {
            float* of = (float*)out + (size_t)d * HC + c0;
            #pragma unroll
            for (int j = 0; j < CPL; ++j) of[j] = vals[j];
        } else {
            // bf16 output, packed stores
            unsigned short* ob = (unsigned short*)out + (size_t)d * HC + c0;
            #pragma unroll
            for (int v = 0; v < NV; ++v) {
                uint4 pk;
                pk.x = pk2(vals[v * 8 + 0], vals[v * 8 + 1]);
                pk.y = pk2(vals[v * 8 + 2], vals[v * 8 + 3]);
                pk.z = pk2(vals[v * 8 + 4], vals[v * 8 + 5]);
                pk.w = pk2(vals[v * 8 + 6], vals[v * 8 + 7]);
                *(uint4*)(ob + v * 8) = pk;
            }
        }
    }
}

// ---------- BatchNorm (bf16 input) ----------
__global__ __launch_bounds__(256) void bn_stats_k(const unsigned short* __restrict__ x,
                                                  float* __restrict__ sum,
                                                  float* __restrict__ sumsq, int n) {
    __shared__ float ss[256], sq[256];
    int t = threadIdx.x;
    int c = t & 127, half = t >> 7;
    float s = 0.f, s2 = 0.f;
    for (int r = blockIdx.x * 2 + half; r < n; r += gridDim.x * 2) {
        float v = u16f(x[(size_t)r * 128 + c]);
        s += v; s2 += v * v;
    }
    ss[t] = s; sq[t] = s2;
    __syncthreads();
    if (t < 128) {
        s = ss[t] + ss[t + 128];
        s2 = sq[t] + sq[t + 128];
        atomicAdd(&sum[c], s);
        atomicAdd(&sumsq[c], s2);
    }
}

// 4 channels per thread; x bf16, skip bf16 (or null), y bf16
__global__ void bn_apply_k(const unsigned short* __restrict__ x,
                           const unsigned short* __restrict__ skip,
                           unsigned short* __restrict__ y,
                           const float* __restrict__ sum, const float* __restrict__ sumsq,
                           const float* __restrict__ g, const float* __restrict__ be, int n) {
    int gid = blockIdx.x * 256 + threadIdx.x;
    if (gid >= n * 32) return;
    int e0 = gid * 4;
    int c0 = e0 & 127;
    const float invN = 1.f / (float)N_NODES;
    float4 gg = *(const float4*)(g + c0);
    float4 bb = *(const float4*)(be + c0);
    float4 sm = *(const float4*)(sum + c0);
    float4 sq = *(const float4*)(sumsq + c0);
    ushort4 xv = *(const ushort4*)(x + e0);
    float vx[4] = { u16f(xv.x), u16f(xv.y), u16f(xv.z), u16f(xv.w) };
    float mg[4] = { gg.x, gg.y, gg.z, gg.w };
    float mb[4] = { bb.x, bb.y, bb.z, bb.w };
    float ms[4] = { sm.x, sm.y, sm.z, sm.w };
    float mq[4] = { sq.x, sq.y, sq.z, sq.w };
    float sk[4] = { 0.f, 0.f, 0.f, 0.f };
    if (skip) {
        ushort4 sv = *(const ushort4*)(skip + e0);
        sk[0] = u16f(sv.x); sk[1] = u16f(sv.y); sk[2] = u16f(sv.z); sk[3] = u16f(sv.w);
    }
    unsigned short o[4];
    #pragma unroll
    for (int j = 0; j < 4; ++j) {
        float mean = ms[j] * invN;
        float var = fmaxf(mq[j] * invN - mean * mean, 0.f);
        float inv = rsqrtf(var + BN_EPS);
        float v = (vx[j] - mean) * inv * mg[j] + mb[j];
        if (skip) v += SKIPC * sk[j];
        o[j] = f2bu(fmaxf(v, 0.f));
    }
    *(ushort4*)(y + e0) = make_ushort4(o[0], o[1], o[2], o[3]);
}

// ---------- launch ----------
extern "C" void kernel_launch(void* const* d_in, const int* in_sizes, int n_in,
                              void* d_out, int out_size, void* d_ws, size_t ws_size,
                              hipStream_t stream) {
    const void* x   = d_in[0];
    const void* W0  = d_in[1];
    const void* as0 = d_in[2];
    const void* ad0 = d_in[3];
    const void* b0  = d_in[4];
    const void* g0  = d_in[5];
    const void* be0 = d_in[6];
    const void* W1  = d_in[7];
    const void* as1 = d_in[8];
    const void* ad1 = d_in[9];
    const void* b1  = d_in[10];
    const void* g1  = d_in[11];
    const void* be1 = d_in[12];
    const void* W2  = d_in[13];
    const void* as2 = d_in[14];
    const void* ad2 = d_in[15];
    const void* b2  = d_in[16];
    const int* ei = (const int*)d_in[17];

    char* w = (char*)d_ws;
    size_t off = 0;
    auto alloc = [&](size_t bytes) -> void* {
        void* p = w + off;
        off = (off + bytes + 255) & ~(size_t)255;
        return p;
    };
    unsigned short* hAgg = (unsigned short*)alloc((size_t)N_NODES * 128 * 2);  // agg out (bf16)
    unsigned short* hbf  = (unsigned short*)alloc((size_t)N_NODES * 128 * 2);  // gemm out / gather src
    unsigned short* hS   = (unsigned short*)alloc((size_t)N_NODES * 128 * 2);  // bn0 out (skip)
    unsigned short* hI   = (unsigned short*)alloc((size_t)N_NODES * 128 * 2);  // bn1 out
    float* als = (float*)alloc((size_t)N_NODES * 4 * 4);
    float* ald = (float*)alloc((size_t)N_NODES * 4 * 4);
    unsigned short* Wb0 = (unsigned short*)alloc((size_t)128 * 128 * 2);
    unsigned short* Wb1 = (unsigned short*)alloc((size_t)128 * 128 * 2);
    unsigned short* Wb2 = (unsigned short*)alloc((size_t)40 * 128 * 2);
    float* prm = (float*)alloc(2048 * 4);
    // contiguous zero-region: bcnt[NB] | bn0[256] | bn1[256]
    int* zreg = (int*)alloc((size_t)(NB + 512) * 4);
    int* bcnt = zreg;
    float* bn0 = (float*)(zreg + NB);
    float* bn1 = bn0 + 256;
    int* row_ptr = (int*)alloc((size_t)(N_NODES + 1) * 4);
    int* ssrc    = (int*)alloc((size_t)TOT_EDGES * 4);
    unsigned int* pairs = (unsigned int*)alloc((size_t)NB * BCAP * 4);
    int* bbase   = (int*)alloc((size_t)NB * 4);
    int* fflag   = (int*)alloc(256);

    float* pAs0 = prm + 0,   * pAd0 = prm + 128,  * pB0 = prm + 256;
    float* pG0  = prm + 384, * pBe0 = prm + 512;
    float* pAs1 = prm + 640, * pAd1 = prm + 768,  * pB1 = prm + 896;
    float* pG1  = prm + 1024,* pBe1 = prm + 1152;
    float* pAs2 = prm + 1280,* pAd2 = prm + 1320, * pB2 = prm + 1360;

    if (off > ws_size) {
        zero_out_k<<<(out_size + 255) / 256, 256, 0, stream>>>((unsigned short*)d_out, out_size);
        return;
    }

    const int MB = (((N_NODES + 15) / 16) + 3) / 4;
    const int AB = (N_NODES * 64 + 255) / 256;
    const int XB4 = (N_NODES * 32 + 255) / 256;

    // --- dtype detection + bucketed CSR build (single upfront memset) ---
    fdetect_k<<<1, 256, 0, stream>>>((const unsigned int*)W0, fflag);
    hipMemsetAsync(zreg, 0, (size_t)(NB + 512) * 4, stream);
    binA_k<<<(N_EDGES + 4095) / 4096, 256, 0, stream>>>(ei, bcnt, pairs);
    bucketscan_k<<<1, 256, 0, stream>>>(bcnt, bbase, row_ptr);
    binB_k<<<NB, 256, 0, stream>>>(bcnt, bbase, pairs, row_ptr, ssrc);

    // --- param conversion ---
    wconv_all_k<<<(37888 + 255) / 256, 256, 0, stream>>>(W0, W1, W2, Wb0, Wb1, Wb2, fflag);
    Cvt13 jobs;
    const void* srcs[13] = { as0, ad0, b0, g0, be0, as1, ad1, b1, g1, be1, as2, ad2, b2 };
    float* dsts[13] = { pAs0, pAd0, pB0, pG0, pBe0, pAs1, pAd1, pB1, pG1, pBe1, pAs2, pAd2, pB2 };
    int ns[13] = { 128,128,128,128,128, 128,128,128,128,128, 40,40,40 };
    for (int i = 0; i < 13; ++i) { jobs.src[i] = srcs[i]; jobs.dst[i] = dsts[i]; jobs.n[i] = ns[i]; }
    cvt_all_k<<<13, 256, 0, stream>>>(jobs, fflag);

    // --- layer 0 ---
    mfma_x_k<<<MB, 256, 0, stream>>>(x, Wb0, hbf, N_NODES, fflag);
    al_k<4, 32><<<(N_NODES * 4 + 255) / 256, 256, 0, stream>>>((const __hip_bfloat16*)hbf, pAs0, pAd0, als, ald, N_NODES);
    agg4_k<4, 32, 8, 16, false><<<AB, 256, 0, stream>>>(hbf, als, ald, pB0, row_ptr, ssrc, hAgg, fflag, N_NODES);
    bn_stats_k<<<256, 256, 0, stream>>>(hAgg, bn0, bn0 + 128, N_NODES);
    bn_apply_k<<<XB4, 256, 0, stream>>>(hAgg, nullptr, hS, bn0, bn0 + 128, pG0, pBe0, N_NODES);
    // hS = relu(bn(...)) = skip (bf16)

    // --- layer 1 ---
    mfma_b_k<<<MB, 256, 0, stream>>>(hS, Wb1, hbf, N_NODES);
    al_k<4, 32><<<(N_NODES * 4 + 255) / 256, 256, 0, stream>>>((const __hip_bfloat16*)hbf, pAs1, pAd1, als, ald, N_NODES);
    agg4_k<4, 32, 8, 16, false><<<AB, 256, 0, stream>>>(hbf, als, ald, pB1, row_ptr, ssrc, hAgg, fflag, N_NODES);
    bn_stats_k<<<256, 256, 0, stream>>>(hAgg, bn1, bn1 + 128, N_NODES);
    bn_apply_k<<<XB4, 256, 0, stream>>>(hAgg, hS, hI, bn1, bn1 + 128, pG1, pBe1, N_NODES);
    // hI = relu(bn(...) + 0.5*skip) (bf16)

    // --- layer 2 ---
    mfma_b40_k<<<MB, 256, 0, stream>>>(hI, Wb2, hbf, N_NODES);
    al_k<1, 40><<<(N_NODES + 255) / 256, 256, 0, stream>>>((const __hip_bfloat16*)hbf, pAs2, pAd2, als, ald, N_NODES);
    agg4_k<1, 40, 8, 8, true><<<AB, 256, 0, stream>>>(hbf, als, ald, pB2, row_ptr, ssrc, d_out, fflag, N_NODES);
}

// Round 12
// 365.563 us; speedup vs baseline: 1.1449x; 1.0567x over previous
//
#include <hip/hip_runtime.h>
#include <hip/hip_bf16.h>
#include <stdint.h>

#define N_NODES 50000
#define N_EDGES 800000
#define TOT_EDGES (N_EDGES + N_NODES)
#define DIM 128
#define NEG 0.2f
#define BN_EPS 1e-5f
#define SKIPC 0.5f
#define NB 196          // buckets of 256 dst nodes
#define BCAP 6144       // per-bucket capacity (mean 4082, +31 sigma)

typedef __attribute__((ext_vector_type(8))) short short8;
typedef __attribute__((ext_vector_type(4))) float f32x4;

// ---------- helpers ----------
__device__ inline float bf2f(__hip_bfloat16 v) { return __bfloat162float(v); }
__device__ inline float u16f(unsigned short u) { return __uint_as_float(((unsigned int)u) << 16); }
__device__ inline unsigned short f2bu(float f) {
    __hip_bfloat16 b = __float2bfloat16(f);
    return *(unsigned short*)&b;
}
__device__ inline void fma8(float* acc, float ex, uint4 u) {
    acc[0] += ex * u16f((unsigned short)(u.x & 0xFFFFu));
    acc[1] += ex * u16f((unsigned short)(u.x >> 16));
    acc[2] += ex * u16f((unsigned short)(u.y & 0xFFFFu));
    acc[3] += ex * u16f((unsigned short)(u.y >> 16));
    acc[4] += ex * u16f((unsigned short)(u.z & 0xFFFFu));
    acc[5] += ex * u16f((unsigned short)(u.z >> 16));
    acc[6] += ex * u16f((unsigned short)(u.w & 0xFFFFu));
    acc[7] += ex * u16f((unsigned short)(u.w >> 16));
}
__device__ inline unsigned int pk2(float a, float b) {
    return (unsigned int)f2bu(a) | ((unsigned int)f2bu(b) << 16);
}

// ---------- fallback (ws too small) ----------
__global__ void zero_out_k(unsigned short* out, int n) {
    int g = blockIdx.x * 256 + threadIdx.x;
    if (g < n) out[g] = 0;
}

// ---------- float dtype detection: fflag=1 => bf16, 0 => f32 ----------
__global__ void fdetect_k(const unsigned int* __restrict__ w0, int* __restrict__ fflag) {
    __shared__ int cs;
    if (threadIdx.x == 0) cs = 0;
    __syncthreads();
    unsigned int w = w0[threadIdx.x];
    float v0 = u16f((unsigned short)(w & 0xFFFFu));
    float a = fabsf(v0);
    int sane = (a < 2.0f && (a > 1e-20f || v0 == 0.0f)) ? 1 : 0;
    atomicAdd(&cs, sane);
    __syncthreads();
    if (threadIdx.x == 0) fflag[0] = (cs >= 128) ? 1 : 0;
}

// ---------- CSR build, bucketed (self-detects int64/int32 edges) ----------
__global__ __launch_bounds__(256) void binA_k(const int* __restrict__ ei,
                                              int* __restrict__ bcnt,
                                              unsigned int* __restrict__ pairs) {
    __shared__ int cnt[NB], base[NB], cur[NB];
    __shared__ int sf;
    int t = threadIdx.x;
    if (t == 0) sf = 0;
    for (int i = t; i < NB; i += 256) cnt[i] = 0;
    __syncthreads();
    if (t < 16 && ei[2 * t + 1] != 0) atomicOr(&sf, 1);
    __syncthreads();
    int f = (sf == 0);   // 1 => int64
    int b0 = blockIdx.x * 4096;
    unsigned int pk[16];
    int bk[16];
    #pragma unroll
    for (int j = 0; j < 16; ++j) {
        int g = b0 + j * 256 + t;
        bk[j] = -1;
        if (g < N_EDGES) {
            int s, d;
            if (f) { s = ei[2 * g]; d = ei[2 * (N_EDGES + g)]; }
            else   { s = ei[g];     d = ei[N_EDGES + g]; }
            if ((unsigned)d < N_NODES && (unsigned)s < N_NODES) {
                bk[j] = d >> 8;
                pk[j] = (unsigned int)s | ((unsigned int)(d & 255) << 16);
                atomicAdd(&cnt[bk[j]], 1);
            }
        }
    }
    __syncthreads();
    if (t < NB) {
        int c = cnt[t];
        base[t] = c ? atomicAdd(&bcnt[t], c) : 0;
        cur[t] = 0;
    }
    __syncthreads();
    #pragma unroll
    for (int j = 0; j < 16; ++j) {
        if (bk[j] >= 0) {
            int off = base[bk[j]] + atomicAdd(&cur[bk[j]], 1);
            if (off < BCAP) pairs[(size_t)bk[j] * BCAP + off] = pk[j];
        }
    }
}

__global__ __launch_bounds__(256) void bucketscan_k(const int* __restrict__ bcnt,
                                                    int* __restrict__ bbase,
                                                    int* __restrict__ row_ptr) {
    __shared__ int sm[256];
    int t = threadIdx.x;
    int v = 0;
    if (t < NB) {
        int nn = min(256, N_NODES - t * 256);
        v = min(bcnt[t], BCAP) + nn;
    }
    sm[t] = v;
    __syncthreads();
    for (int off = 1; off < 256; off <<= 1) {
        int x = (t >= off) ? sm[t - off] : 0;
        __syncthreads();
        sm[t] += x;
        __syncthreads();
    }
    if (t < NB) bbase[t] = sm[t] - v;
    if (t == 255) row_ptr[N_NODES] = sm[255];
}

__global__ __launch_bounds__(256) void binB_k(const int* __restrict__ bcnt,
                                              const int* __restrict__ bbase,
                                              const unsigned int* __restrict__ pairs,
                                              int* __restrict__ row_ptr,
                                              int* __restrict__ ssrc) {
    __shared__ int cntL[256], scanL[256], curL[256];
    int b = blockIdx.x, t = threadIdx.x;
    int n0 = b * 256;
    int nn = min(256, N_NODES - n0);
    int cnt_b = min(bcnt[b], BCAP);
    const unsigned int* P = pairs + (size_t)b * BCAP;
    cntL[t] = (t < nn) ? 1 : 0;
    __syncthreads();
    for (int i = t; i < cnt_b; i += 256)
        atomicAdd(&cntL[P[i] >> 16], 1);
    __syncthreads();
    int v = cntL[t];
    scanL[t] = v;
    __syncthreads();
    for (int off = 1; off < 256; off <<= 1) {
        int x = (t >= off) ? scanL[t - off] : 0;
        __syncthreads();
        scanL[t] += x;
        __syncthreads();
    }
    int excl = scanL[t] - v;
    int gbase = bbase[b];
    if (t < nn) row_ptr[n0 + t] = gbase + excl;
    curL[t] = excl;
    __syncthreads();
    if (t < nn) {
        int pos = atomicAdd(&curL[t], 1);
        ssrc[gbase + pos] = n0 + t;
    }
    for (int i = t; i < cnt_b; i += 256) {
        unsigned int p = P[i];
        int pos = atomicAdd(&curL[p >> 16], 1);
        ssrc[gbase + pos] = (int)(p & 0xFFFFu);
    }
}

// ---------- merged W-convert + small-param convert ----------
// blocks 0..147: W0/W1/W2 -> bf16 (same [M][K] layout, into extended buffers)
// blocks 148..160: 13 small params -> f32
struct PrepJobs { const void* src[13]; float* dst[13]; int n[13]; };
__global__ __launch_bounds__(256) void wcvt_k(const void* __restrict__ W0,
                                              const void* __restrict__ W1,
                                              const void* __restrict__ W2,
                                              unsigned short* __restrict__ Wb0,
                                              unsigned short* __restrict__ Wb1,
                                              unsigned short* __restrict__ Wb2,
                                              PrepJobs jobs,
                                              const int* __restrict__ fflag) {
    int f = fflag[0];
    int b = blockIdx.x;
    if (b < 148) {
        int g = b * 256 + threadIdx.x;
        const void* W; unsigned short* Wb; int idx;
        if (g < 16384)        { W = W0; Wb = Wb0; idx = g; }
        else if (g < 32768)   { W = W1; Wb = Wb1; idx = g - 16384; }
        else if (g < 37888)   { W = W2; Wb = Wb2; idx = g - 32768; }
        else return;
        if (f) Wb[idx] = ((const unsigned short*)W)[idx];
        else   Wb[idx] = f2bu(((const float*)W)[idx]);
    } else {
        int j = b - 148;
        int n = jobs.n[j];
        const void* s = jobs.src[j];
        float* d = jobs.dst[j];
        for (int i = threadIdx.x; i < n; i += 256)
            d[i] = f ? bf2f(((const __hip_bfloat16*)s)[i]) : ((const float*)s)[i];
    }
}

// ---------- extended-weight build: Wext rows encode attention vectors ----------
// Layer 0/1 (bf16 Wb [136][128]): row 128+dir*4+hh = sum_c a[hh][c]*W[hh*32+c][:]
// Layer 2 (bf16 Wb2 [42][128]):   row 40+dir      = sum_c a[c]*W2[c][:]
__global__ __launch_bounds__(256) void wext_k(unsigned short* __restrict__ Wb0,
                                              unsigned short* __restrict__ Wb1,
                                              unsigned short* __restrict__ Wb2,
                                              const float* __restrict__ pAs0, const float* __restrict__ pAd0,
                                              const float* __restrict__ pAs1, const float* __restrict__ pAd1,
                                              const float* __restrict__ pAs2, const float* __restrict__ pAd2) {
    int g = blockIdx.x * 256 + threadIdx.x;
    if (g < 2048) {
        int layer = g >> 10;           // 0 or 1
        int gi = g & 1023;
        int rowq = gi >> 7;            // 0..7
        int k = gi & 127;
        int hh = rowq & 3, dir = rowq >> 2;
        unsigned short* Wb = layer ? Wb1 : Wb0;
        const float* p = layer ? (dir ? pAd1 : pAs1) : (dir ? pAd0 : pAs0);
        float v = 0.f;
        #pragma unroll
        for (int c = 0; c < 32; ++c)
            v += p[hh * 32 + c] * u16f(Wb[(size_t)(hh * 32 + c) * 128 + k]);
        Wb[(size_t)(128 + dir * 4 + hh) * 128 + k] = f2bu(v);
    } else if (g < 2304) {
        int gi = g - 2048;
        int dir = gi >> 7;
        int k = gi & 127;
        const float* p = dir ? pAd2 : pAs2;
        float v = 0.f;
        #pragma unroll
        for (int c = 0; c < 40; ++c)
            v += p[c] * u16f(Wb2[(size_t)c * 128 + k]);
        Wb2[(size_t)(40 + dir) * 128 + k] = f2bu(v);
    }
}

// ---------- MFMA GEMM with AL columns ----------
// Y[n][MV] bf16 = X[n][128] @ W^T; Wb has ALBASE+2*NH valid rows; columns
// [ALBASE, ALBASE+NH) -> als, [ALBASE+NH, ALBASE+2NH) -> ald (f32 stores).
// All register indices static (t,r unrolled) — no dynamic indexing (round-9 trap).
template<int MT, int MV, int ALBASE, int NH, bool BF16IN>
__device__ inline void mfma_body(const unsigned short* __restrict__ Xb,
                                 const float* __restrict__ Xf,
                                 const unsigned short* __restrict__ Wb,
                                 unsigned short* __restrict__ Y,
                                 float* __restrict__ als, float* __restrict__ ald, int n) {
    const int MROWS = ALBASE + 2 * NH;
    int wave = (blockIdx.x * blockDim.x + threadIdx.x) >> 6;
    int r0 = wave * 16;
    if (r0 >= n) return;
    int lane = threadIdx.x & 63;
    int m = lane & 15, quad = lane >> 4;
    f32x4 acc[MT];
    #pragma unroll
    for (int t = 0; t < MT; ++t) acc[t] = (f32x4){0.f, 0.f, 0.f, 0.f};
    int arow = min(r0 + m, n - 1);

    #pragma unroll
    for (int kc = 0; kc < 4; ++kc) {
        int k0 = kc * 32 + quad * 8;
        short8 a;
        if (BF16IN) {
            a = *(const short8*)(Xb + (size_t)arow * 128 + k0);
        } else {
            const float* xp = Xf + (size_t)arow * 128 + k0;
            float4 x0 = *(const float4*)xp;
            float4 x1 = *(const float4*)(xp + 4);
            a[0] = (short)f2bu(x0.x); a[1] = (short)f2bu(x0.y);
            a[2] = (short)f2bu(x0.z); a[3] = (short)f2bu(x0.w);
            a[4] = (short)f2bu(x1.x); a[5] = (short)f2bu(x1.y);
            a[6] = (short)f2bu(x1.z); a[7] = (short)f2bu(x1.w);
        }
        #pragma unroll
        for (int t = 0; t < MT; ++t) {
            int col = t * 16 + m;
            short8 b;
            if (col < MROWS) b = *(const short8*)(Wb + (size_t)col * 128 + k0);
            else             b = (short8){0,0,0,0,0,0,0,0};
            acc[t] = __builtin_amdgcn_mfma_f32_16x16x32_bf16(a, b, acc[t], 0, 0, 0);
        }
    }

    #pragma unroll
    for (int t = 0; t < MT; ++t) {
        int col = t * 16 + m;
        #pragma unroll
        for (int r = 0; r < 4; ++r) {
            int row = r0 + quad * 4 + r;
            if (row >= n) continue;
            if (col < MV) {
                Y[(size_t)row * MV + col] = f2bu(acc[t][r]);
            } else if (col < ALBASE + NH) {
                als[row * NH + (col - ALBASE)] = acc[t][r];
            } else if (col < ALBASE + 2 * NH) {
                ald[row * NH + (col - ALBASE - NH)] = acc[t][r];
            }
        }
    }
}

__global__ __launch_bounds__(256) void mfma_x_k(const void* __restrict__ X,
                                                const unsigned short* __restrict__ Wb,
                                                unsigned short* __restrict__ Y,
                                                float* __restrict__ als, float* __restrict__ ald,
                                                int n, const int* __restrict__ fflag) {
    if (fflag[0]) mfma_body<9, 128, 128, 4, true>((const unsigned short*)X, nullptr, Wb, Y, als, ald, n);
    else          mfma_body<9, 128, 128, 4, false>(nullptr, (const float*)X, Wb, Y, als, ald, n);
}

__global__ __launch_bounds__(256) void mfma_b_k(const unsigned short* __restrict__ X,
                                                const unsigned short* __restrict__ Wb,
                                                unsigned short* __restrict__ Y,
                                                float* __restrict__ als, float* __restrict__ ald, int n) {
    mfma_body<9, 128, 128, 4, true>(X, nullptr, Wb, Y, als, ald, n);
}

__global__ __launch_bounds__(256) void mfma_b40_k(const unsigned short* __restrict__ X,
                                                  const unsigned short* __restrict__ Wb,
                                                  unsigned short* __restrict__ Y,
                                                  float* __restrict__ als, float* __restrict__ ald, int n) {
    mfma_body<3, 40, 40, 1, true>(X, nullptr, Wb, Y, als, ald, n);
}

// ---------- GAT aggregation: 2-deep pipelined gather, bf16 output ----------
template<int H, int C, int LPG, int CPL, bool FINAL>
__global__ __launch_bounds__(256) void agg4_k(const unsigned short* __restrict__ hbuf,
                                              const float* __restrict__ als,
                                              const float* __restrict__ ald,
                                              const float* __restrict__ bias,
                                              const int* __restrict__ row_ptr,
                                              const int* __restrict__ ssrc,
                                              void* __restrict__ out,
                                              const int* __restrict__ fflag, int n) {
    const int HC = H * C;
    const int G = 64 / LPG;
    const int NV = CPL / 8;
    int gw = (blockIdx.x * blockDim.x + threadIdx.x) >> 6;
    if (gw >= n) return;
    int lane = threadIdx.x & 63;
    int grp = lane / LPG;
    int sl  = lane % LPG;
    int c0 = sl * CPL;
    bool act = c0 < HC;
    int hl = act ? (c0 / C) : 0;
    int d = gw;
    int beg = row_ptr[d], end = row_ptr[d + 1];
    float adh = ald[d * H + hl];

    float denom = 0.f;
    float acc[CPL];
    #pragma unroll
    for (int j = 0; j < CPL; ++j) acc[j] = 0.f;

    int i0 = beg + grp;
    bool h0 = i0 < end;
    bool h1 = (i0 + G) < end;
    float al0 = 0.f, al1 = 0.f;
    uint4 u0[NV], u1[NV];
    if (h0) {
        int s = ssrc[i0];
        al0 = als[s * H + hl];
        if (act) {
            const uint4* hp = (const uint4*)(hbuf + (size_t)s * HC + c0);
            #pragma unroll
            for (int v = 0; v < NV; ++v) u0[v] = hp[v];
        }
    }
    if (h1) {
        int s = ssrc[i0 + G];
        al1 = als[s * H + hl];
        if (act) {
            const uint4* hp = (const uint4*)(hbuf + (size_t)s * HC + c0);
            #pragma unroll
            for (int v = 0; v < NV; ++v) u1[v] = hp[v];
        }
    }
    int inext = i0 + 2 * G;

    while (h0) {
        bool h2 = inext < end;
        float al2 = 0.f;
        uint4 u2[NV];
        if (h2) {
            int s = ssrc[inext];
            al2 = als[s * H + hl];
            if (act) {
                const uint4* hp = (const uint4*)(hbuf + (size_t)s * HC + c0);
                #pragma unroll
                for (int v = 0; v < NV; ++v) u2[v] = hp[v];
            }
        }
        float t = al0 + adh;
        t = t > 0.f ? t : NEG * t;
        float ex = __expf(t);
        denom += ex;
        if (act) {
            #pragma unroll
            for (int v = 0; v < NV; ++v) fma8(acc + v * 8, ex, u0[v]);
        }
        h0 = h1; al0 = al1;
        #pragma unroll
        for (int v = 0; v < NV; ++v) u0[v] = u1[v];
        h1 = h2; al1 = al2;
        #pragma unroll
        for (int v = 0; v < NV; ++v) u1[v] = u2[v];
        inext += G;
    }

    #pragma unroll
    for (int off = LPG; off < 64; off <<= 1) {
        denom += __shfl_xor(denom, off, 64);
        #pragma unroll
        for (int j = 0; j < CPL; ++j) acc[j] += __shfl_xor(acc[j], off, 64);
    }

    if (grp == 0 && act) {
        float inv = 1.f / denom;
        float vals[CPL];
        #pragma unroll
        for (int j = 0; j < CPL; ++j) vals[j] = acc[j] * inv + bias[c0 + j];
        if (FINAL && !fflag[0]) {
            float* of = (float*)out + (size_t)d * HC + c0;
            #pragma unroll
            for (int j = 0; j < CPL; ++j) of[j] = vals[j];
        } else {
            unsigned short* ob = (unsigned short*)out + (size_t)d * HC + c0;
            #pragma unroll
            for (int v = 0; v < NV; ++v) {
                uint4 pk;
                pk.x = pk2(vals[v * 8 + 0], vals[v * 8 + 1]);
                pk.y = pk2(vals[v * 8 + 2], vals[v * 8 + 3]);
                pk.z = pk2(vals[v * 8 + 4], vals[v * 8 + 5]);
                pk.w = pk2(vals[v * 8 + 6], vals[v * 8 + 7]);
                *(uint4*)(ob + v * 8) = pk;
            }
        }
    }
}

// ---------- BatchNorm (bf16 input) ----------
__global__ __launch_bounds__(256) void bn_stats_k(const unsigned short* __restrict__ x,
                                                  float* __restrict__ sum,
                                                  float* __restrict__ sumsq, int n) {
    __shared__ float ss[256], sq[256];
    int t = threadIdx.x;
    int c = t & 127, half = t >> 7;
    float s = 0.f, s2 = 0.f;
    for (int r = blockIdx.x * 2 + half; r < n; r += gridDim.x * 2) {
        float v = u16f(x[(size_t)r * 128 + c]);
        s += v; s2 += v * v;
    }
    ss[t] = s; sq[t] = s2;
    __syncthreads();
    if (t < 128) {
        s = ss[t] + ss[t + 128];
        s2 = sq[t] + sq[t + 128];
        atomicAdd(&sum[c], s);
        atomicAdd(&sumsq[c], s2);
    }
}

__global__ void bn_apply_k(const unsigned short* __restrict__ x,
                           const unsigned short* __restrict__ skip,
                           unsigned short* __restrict__ y,
                           const float* __restrict__ sum, const float* __restrict__ sumsq,
                           const float* __restrict__ g, const float* __restrict__ be, int n) {
    int gid = blockIdx.x * 256 + threadIdx.x;
    if (gid >= n * 32) return;
    int e0 = gid * 4;
    int c0 = e0 & 127;
    const float invN = 1.f / (float)N_NODES;
    float4 gg = *(const float4*)(g + c0);
    float4 bb = *(const float4*)(be + c0);
    float4 sm = *(const float4*)(sum + c0);
    float4 sq = *(const float4*)(sumsq + c0);
    ushort4 xv = *(const ushort4*)(x + e0);
    float vx[4] = { u16f(xv.x), u16f(xv.y), u16f(xv.z), u16f(xv.w) };
    float mg[4] = { gg.x, gg.y, gg.z, gg.w };
    float mb[4] = { bb.x, bb.y, bb.z, bb.w };
    float ms[4] = { sm.x, sm.y, sm.z, sm.w };
    float mq[4] = { sq.x, sq.y, sq.z, sq.w };
    float sk[4] = { 0.f, 0.f, 0.f, 0.f };
    if (skip) {
        ushort4 sv = *(const ushort4*)(skip + e0);
        sk[0] = u16f(sv.x); sk[1] = u16f(sv.y); sk[2] = u16f(sv.z); sk[3] = u16f(sv.w);
    }
    unsigned short o[4];
    #pragma unroll
    for (int j = 0; j < 4; ++j) {
        float mean = ms[j] * invN;
        float var = fmaxf(mq[j] * invN - mean * mean, 0.f);
        float inv = rsqrtf(var + BN_EPS);
        float v = (vx[j] - mean) * inv * mg[j] + mb[j];
        if (skip) v += SKIPC * sk[j];
        o[j] = f2bu(fmaxf(v, 0.f));
    }
    *(ushort4*)(y + e0) = make_ushort4(o[0], o[1], o[2], o[3]);
}

// ---------- launch ----------
extern "C" void kernel_launch(void* const* d_in, const int* in_sizes, int n_in,
                              void* d_out, int out_size, void* d_ws, size_t ws_size,
                              hipStream_t stream) {
    const void* x   = d_in[0];
    const void* W0  = d_in[1];
    const void* as0 = d_in[2];
    const void* ad0 = d_in[3];
    const void* b0  = d_in[4];
    const void* g0  = d_in[5];
    const void* be0 = d_in[6];
    const void* W1  = d_in[7];
    const void* as1 = d_in[8];
    const void* ad1 = d_in[9];
    const void* b1  = d_in[10];
    const void* g1  = d_in[11];
    const void* be1 = d_in[12];
    const void* W2  = d_in[13];
    const void* as2 = d_in[14];
    const void* ad2 = d_in[15];
    const void* b2  = d_in[16];
    const int* ei = (const int*)d_in[17];

    char* w = (char*)d_ws;
    size_t off = 0;
    auto alloc = [&](size_t bytes) -> void* {
        void* p = w + off;
        off = (off + bytes + 255) & ~(size_t)255;
        return p;
    };
    unsigned short* hAgg = (unsigned short*)alloc((size_t)N_NODES * 128 * 2);
    unsigned short* hbf  = (unsigned short*)alloc((size_t)N_NODES * 128 * 2);
    unsigned short* hS   = (unsigned short*)alloc((size_t)N_NODES * 128 * 2);
    unsigned short* hI   = (unsigned short*)alloc((size_t)N_NODES * 128 * 2);
    float* als = (float*)alloc((size_t)N_NODES * 4 * 4);
    float* ald = (float*)alloc((size_t)N_NODES * 4 * 4);
    unsigned short* Wb0 = (unsigned short*)alloc((size_t)136 * 128 * 2);
    unsigned short* Wb1 = (unsigned short*)alloc((size_t)136 * 128 * 2);
    unsigned short* Wb2 = (unsigned short*)alloc((size_t)42 * 128 * 2);
    float* prm = (float*)alloc(2048 * 4);
    // contiguous zero-region: bcnt[NB] | bn0[256] | bn1[256]
    int* zreg = (int*)alloc((size_t)(NB + 512) * 4);
    int* bcnt = zreg;
    float* bn0 = (float*)(zreg + NB);
    float* bn1 = bn0 + 256;
    int* row_ptr = (int*)alloc((size_t)(N_NODES + 1) * 4);
    int* ssrc    = (int*)alloc((size_t)TOT_EDGES * 4);
    unsigned int* pairs = (unsigned int*)alloc((size_t)NB * BCAP * 4);
    int* bbase   = (int*)alloc((size_t)NB * 4);
    int* fflag   = (int*)alloc(256);

    float* pAs0 = prm + 0,   * pAd0 = prm + 128,  * pB0 = prm + 256;
    float* pG0  = prm + 384, * pBe0 = prm + 512;
    float* pAs1 = prm + 640, * pAd1 = prm + 768,  * pB1 = prm + 896;
    float* pG1  = prm + 1024,* pBe1 = prm + 1152;
    float* pAs2 = prm + 1280,* pAd2 = prm + 1320, * pB2 = prm + 1360;

    if (off > ws_size) {
        zero_out_k<<<(out_size + 255) / 256, 256, 0, stream>>>((unsigned short*)d_out, out_size);
        return;
    }

    const int MB = (((N_NODES + 15) / 16) + 3) / 4;
    const int AB = (N_NODES * 64 + 255) / 256;
    const int XB4 = (N_NODES * 32 + 255) / 256;

    // --- dtype detection + bucketed CSR build ---
    fdetect_k<<<1, 256, 0, stream>>>((const unsigned int*)W0, fflag);
    hipMemsetAsync(zreg, 0, (size_t)(NB + 512) * 4, stream);
    binA_k<<<(N_EDGES + 4095) / 4096, 256, 0, stream>>>(ei, bcnt, pairs);
    bucketscan_k<<<1, 256, 0, stream>>>(bcnt, bbase, row_ptr);
    binB_k<<<NB, 256, 0, stream>>>(bcnt, bbase, pairs, row_ptr, ssrc);

    // --- param conversion + extended weights ---
    PrepJobs jobs;
    const void* srcs[13] = { as0, ad0, b0, g0, be0, as1, ad1, b1, g1, be1, as2, ad2, b2 };
    float* dsts[13] = { pAs0, pAd0, pB0, pG0, pBe0, pAs1, pAd1, pB1, pG1, pBe1, pAs2, pAd2, pB2 };
    int ns[13] = { 128,128,128,128,128, 128,128,128,128,128, 40,40,40 };
    for (int i = 0; i < 13; ++i) { jobs.src[i] = srcs[i]; jobs.dst[i] = dsts[i]; jobs.n[i] = ns[i]; }
    wcvt_k<<<161, 256, 0, stream>>>(W0, W1, W2, Wb0, Wb1, Wb2, jobs, fflag);
    wext_k<<<9, 256, 0, stream>>>(Wb0, Wb1, Wb2, pAs0, pAd0, pAs1, pAd1, pAs2, pAd2);

    // --- layer 0 (GEMM emits h + als/ald) ---
    mfma_x_k<<<MB, 256, 0, stream>>>(x, Wb0, hbf, als, ald, N_NODES, fflag);
    agg4_k<4, 32, 8, 16, false><<<AB, 256, 0, stream>>>(hbf, als, ald, pB0, row_ptr, ssrc, hAgg, fflag, N_NODES);
    bn_stats_k<<<256, 256, 0, stream>>>(hAgg, bn0, bn0 + 128, N_NODES);
    bn_apply_k<<<XB4, 256, 0, stream>>>(hAgg, nullptr, hS, bn0, bn0 + 128, pG0, pBe0, N_NODES);
    // hS = relu(bn(...)) = skip (bf16)

    // --- layer 1 ---
    mfma_b_k<<<MB, 256, 0, stream>>>(hS, Wb1, hbf, als, ald, N_NODES);
    agg4_k<4, 32, 8, 16, false><<<AB, 256, 0, stream>>>(hbf, als, ald, pB1, row_ptr, ssrc, hAgg, fflag, N_NODES);
    bn_stats_k<<<256, 256, 0, stream>>>(hAgg, bn1, bn1 + 128, N_NODES);
    bn_apply_k<<<XB4, 256, 0, stream>>>(hAgg, hS, hI, bn1, bn1 + 128, pG1, pBe1, N_NODES);
    // hI = relu(bn(...) + 0.5*skip) (bf16)

    // --- layer 2 ---
    mfma_b40_k<<<MB, 256, 0, stream>>>(hI, Wb2, hbf, als, ald, N_NODES);
    agg4_k<1, 40, 8, 8, true><<<AB, 256, 0, stream>>>(hbf, als, ald, pB2, row_ptr, ssrc, d_out, fflag, N_NODES);
}